// Round 5
// baseline (728.987 us; speedup 1.0000x reference)
//
#include <hip/hip_runtime.h>
#include <hip/hip_bf16.h>

using u16 = unsigned short;
using short8 = __attribute__((ext_vector_type(8))) short;
using f32x4  = __attribute__((ext_vector_type(4))) float;

constexpr int INC_ = 96;
constexpr int D_   = 192;
constexpr int DI_  = 384;

// workspace offsets in floats (re-packed; total unchanged vs R4)
constexpr size_t O_T1   = 0;                        // 8192*96   t1 (f32 NHWC)
constexpr size_t O_T2   = O_T1 + (size_t)8192*96;   // 8192*192  t2
constexpr size_t O_XZ   = O_T2 + (size_t)8192*192;  // 8192*768  xz; later dt_t+yf_t
constexpr size_t O_XC   = O_XZ + (size_t)8192*768;  // 8192*384  xc row-major
constexpr size_t O_DBLT = O_XC + (size_t)8192*384;  // 44*8192   dbl transposed
constexpr size_t O_XCT  = O_DBLT + (size_t)44*8192; // 384*8192  xc transposed
constexpr size_t O_ZST  = O_XCT + (size_t)384*8192; // 384*8192  silu(z) transposed
constexpr size_t O_U    = O_ZST + (size_t)384*8192; // 8192*192  u
constexpr size_t O_V    = O_U  + (size_t)8192*192;  // bf16 arena
// dt_t and yf_t live in the dead xz region (exact fit: 2*384*8192 == 768*8192)
constexpr size_t O_DTT  = O_XZ;
constexpr size_t O_YFT  = O_XZ + (size_t)384*8192;

__device__ __forceinline__ u16 f2b(float f) {
    __hip_bfloat16 h = __float2bfloat16(f);
    return *reinterpret_cast<u16*>(&h);
}

// ---------------- weight transform: [CO][CI][3][3] f32 -> [9][CO][CI] bf16 ----------------
__global__ __launch_bounds__(256) void cvt_w_k(
    const float* __restrict__ src, u16* __restrict__ dst, int CO, int CI)
{
    int total = 9 * CO * CI;
    for (int idx = blockIdx.x * 256 + threadIdx.x; idx < total; idx += gridDim.x * 256) {
        int ci = idx % CI;
        int rem = idx / CI;
        int co = rem % CO;
        int t = rem / CO;
        dst[idx] = f2b(src[((size_t)co * CI + ci) * 9 + t]);
    }
}

// ---------------- x: NCHW f32 -> NHWC bf16 ----------------
__global__ __launch_bounds__(256) void cvt_x_k(
    const float* __restrict__ src, u16* __restrict__ dst)
{
    int idx = blockIdx.x * 256 + threadIdx.x;   // 8192*96
    int ci = idx % 96;
    int px = idx / 96;
    dst[idx] = f2b(src[(((size_t)(px >> 10) * 96 + ci) << 10) | (size_t)(px & 1023)]);
}

// ---------------- 3x3 conv as bf16-MFMA shift-GEMM + BN + exact GELU ----------------
template<int CIN, int COUT, int NTILE, int OUTM>
__global__ __launch_bounds__(256) void conv3x3_mfma_k(
    const u16* __restrict__ Xb, const u16* __restrict__ Wt,
    const float* __restrict__ g, const float* __restrict__ b,
    const float* __restrict__ m, const float* __restrict__ v,
    float* __restrict__ out)
{
    constexpr int LDA = 40;
    constexpr int NT = NTILE / 16;
    __shared__ u16 As[64 * LDA];
    __shared__ u16 Bs[NTILE * LDA];
    const int tid = threadIdx.x;
    const int wave = tid >> 6, lane = tid & 63;
    const int quad = lane >> 4, l16 = lane & 15;
    const int rowBase = blockIdx.x * 64;
    const int colBase = blockIdx.y * NTILE;

    f32x4 acc[NT];
    #pragma unroll
    for (int nt = 0; nt < NT; ++nt)
        #pragma unroll
        for (int i = 0; i < 4; ++i) acc[nt][i] = 0.f;

    const int ar = tid >> 2, aseg = tid & 3;
    const int apx = rowBase + ar;
    const int ah = (apx >> 5) & 31, aw = apx & 31;

    for (int t = 0; t < 9; ++t) {
        const int dr = t / 3 - 1, dc = t % 3 - 1;
        const bool avalid = ((unsigned)(ah + dr) < 32u) && ((unsigned)(aw + dc) < 32u);
        const int apxs = apx + dr * 32 + dc;
        for (int ci0 = 0; ci0 < CIN; ci0 += 32) {
            __syncthreads();
            uint4 va = make_uint4(0u, 0u, 0u, 0u);
            if (avalid)
                va = *(const uint4*)(Xb + (size_t)apxs * CIN + ci0 + aseg * 8);
            *(uint4*)(As + ar * LDA + aseg * 8) = va;
            if (tid < NTILE * 4) {
                int r = tid >> 2, seg = tid & 3;
                uint4 vb = *(const uint4*)(Wt + ((size_t)t * COUT + colBase + r) * CIN + ci0 + seg * 8);
                *(uint4*)(Bs + r * LDA + seg * 8) = vb;
            }
            __syncthreads();
            short8 a = *(const short8*)(As + (wave * 16 + l16) * LDA + quad * 8);
            #pragma unroll
            for (int nt = 0; nt < NT; ++nt) {
                short8 bf = *(const short8*)(Bs + (nt * 16 + l16) * LDA + quad * 8);
                acc[nt] = __builtin_amdgcn_mfma_f32_16x16x32_bf16(a, bf, acc[nt], 0, 0, 0);
            }
        }
    }

    const int px0 = rowBase + wave * 16 + quad * 4;
    #pragma unroll
    for (int nt = 0; nt < NT; ++nt) {
        const int co = colBase + nt * 16 + l16;
        const float sc = g[co] * rsqrtf(v[co] + 1e-5f);
        const float bb = b[co] - m[co] * sc;
        float o[4];
        #pragma unroll
        for (int r = 0; r < 4; ++r) {
            float xv = acc[nt][r] * sc + bb;
            o[r] = 0.5f * xv * (1.f + erff(xv * 0.70710678f));
        }
        if (OUTM == 0) {
            #pragma unroll
            for (int r = 0; r < 4; ++r)
                out[(size_t)(px0 + r) * COUT + co] = o[r];
        } else {
            const int img = px0 >> 10, off = px0 & 1023;
            *(float4*)(out + (((size_t)img * COUT + co) << 10) + off) =
                make_float4(o[0], o[1], o[2], o[3]);
        }
    }
}

// ---------------- generic tiled f32 GEMM: C[M,N] = A[M,K] @ B[N,K]^T ----------------
// ATRANS=1: A stored [K][M] with row stride lda (=M); rows kt..kt+15 must be readable.
// OUTM 0: f32 row-major; 2: bf16 row-major; 3: f32 transposed C_t[col*M+row].
enum { EPI_NONE = 0, EPI_BN_SILU = 1, EPI_SP = 2 };

template<int EPI, int OUTM, int ATRANS>
__global__ __launch_bounds__(256) void gemm_k(
    int M, int N, int K, int lda,
    const float* __restrict__ A, const float* __restrict__ B, void* __restrict__ C,
    const float* __restrict__ p0, const float* __restrict__ p1,
    const float* __restrict__ p2, const float* __restrict__ p3)
{
    __shared__ float As[16][68];
    __shared__ float Bs[16][68];
    const int tid = threadIdx.x;
    const int tx = tid & 15, ty = tid >> 4;
    const int rowBase = blockIdx.x * 64;
    const int colBase = blockIdx.y * 64;
    const int lr = tid >> 2;
    const int kq = (tid & 3) << 2;
    float acc[4][4] = {};
    for (int kt = 0; kt < K; kt += 16) {
        float4 bv = make_float4(0.f, 0.f, 0.f, 0.f);
        int bn = colBase + lr;
        if (bn < N && kt + kq < K)
            bv = *(const float4*)(B + (size_t)bn * K + kt + kq);
        if (ATRANS) {
            const int kk = tid >> 4, seg = tid & 15;
            float4 av = *(const float4*)(A + (size_t)(kt + kk) * lda + rowBase + seg * 4);
            *(float4*)&As[kk][seg * 4] = av;
        } else {
            float4 av = make_float4(0.f, 0.f, 0.f, 0.f);
            if (kt + kq < K)
                av = *(const float4*)(A + (size_t)(rowBase + lr) * lda + kt + kq);
            As[kq+0][lr] = av.x; As[kq+1][lr] = av.y; As[kq+2][lr] = av.z; As[kq+3][lr] = av.w;
        }
        Bs[kq+0][lr] = bv.x; Bs[kq+1][lr] = bv.y; Bs[kq+2][lr] = bv.z; Bs[kq+3][lr] = bv.w;
        __syncthreads();
        #pragma unroll
        for (int kk = 0; kk < 16; ++kk) {
            float4 a = *(const float4*)&As[kk][ty << 2];
            float4 b = *(const float4*)&Bs[kk][tx << 2];
            float ar[4] = {a.x, a.y, a.z, a.w};
            float br[4] = {b.x, b.y, b.z, b.w};
            #pragma unroll
            for (int i = 0; i < 4; ++i)
                #pragma unroll
                for (int jj = 0; jj < 4; ++jj)
                    acc[i][jj] += ar[i] * br[jj];
        }
        __syncthreads();
    }
    #pragma unroll
    for (int jj = 0; jj < 4; ++jj) {
        int col = colBase + (tx << 2) + jj;
        if (col >= N) continue;
        float sc = 0.f, bb = 0.f;
        if (EPI == EPI_BN_SILU) {
            sc = p0[col] * rsqrtf(p3[col] + 1e-5f);
            bb = p1[col] - p2[col] * sc;
        } else if (EPI == EPI_SP) {
            bb = p0[col];
        }
        float o[4];
        #pragma unroll
        for (int i = 0; i < 4; ++i) {
            float xv = acc[i][jj];
            if (EPI == EPI_BN_SILU) {
                xv = xv * sc + bb;
                xv = xv / (1.f + __expf(-xv));
            } else if (EPI == EPI_SP) {
                xv += bb;
                xv = (xv > 20.f) ? xv : log1pf(__expf(xv));
            }
            o[i] = xv;
        }
        if (OUTM == 3) {
            *(float4*)((float*)C + (size_t)col * M + rowBase + (ty << 2)) =
                make_float4(o[0], o[1], o[2], o[3]);
        } else {
            #pragma unroll
            for (int i = 0; i < 4; ++i) {
                size_t idx = (size_t)(rowBase + (ty << 2) + i) * N + col;
                if (OUTM == 2) ((u16*)C)[idx] = f2b(o[i]);
                else           ((float*)C)[idx] = o[i];
            }
        }
    }
}

// ---------------- z-gate extract: zs_t[d][m] = silu(xz[m][384+d]) ----------------
__global__ __launch_bounds__(256) void ztr_k(
    const float* __restrict__ xz, float* __restrict__ zst)
{
    __shared__ float T[64][65];
    const int tid = threadIdx.x;
    const int cl = tid & 63, rq = tid >> 6;
    const int mBase = blockIdx.x * 64, dBase = blockIdx.y * 64;
    #pragma unroll
    for (int rr = 0; rr < 16; ++rr) {
        int ml = rr * 4 + rq;
        float zv = xz[(size_t)(mBase + ml) * 768 + 384 + dBase + cl];
        T[ml][cl] = zv / (1.f + __expf(-zv));
    }
    __syncthreads();
    #pragma unroll
    for (int rr = 0; rr < 16; ++rr) {
        int dl = rr * 4 + rq;
        zst[(size_t)(dBase + dl) * 8192 + mBase + cl] = T[cl][dl];
    }
}

// ---------------- depthwise causal conv (K=4) + SiLU, dual-layout output ----------------
__global__ __launch_bounds__(256) void dwconv_k(
    const float* __restrict__ xz, const float* __restrict__ cw, const float* __restrict__ cb,
    float* __restrict__ xc, float* __restrict__ xct)
{
    __shared__ float T[64][65];
    const int tid = threadIdx.x;
    const int cl = tid & 63, rq = tid >> 6;
    const int mBase = blockIdx.x * 64, cBase = blockIdx.y * 64;
    const int c = cBase + cl;
    const float w0 = cw[c*4+0], w1 = cw[c*4+1], w2 = cw[c*4+2], w3 = cw[c*4+3];
    const float bias = cb[c];
    #pragma unroll
    for (int rr = 0; rr < 16; ++rr) {
        int ml = rr * 4 + rq;
        int bl = mBase + ml;
        int l = bl & 1023;
        float acc = bias + xz[(size_t)bl * 768 + c] * w3;
        if (l >= 1) acc += xz[(size_t)(bl-1) * 768 + c] * w2;
        if (l >= 2) acc += xz[(size_t)(bl-2) * 768 + c] * w1;
        if (l >= 3) acc += xz[(size_t)(bl-3) * 768 + c] * w0;
        float s = acc / (1.f + __expf(-acc));
        xc[(size_t)bl * DI_ + c] = s;
        T[ml][cl] = s;
    }
    __syncthreads();
    #pragma unroll
    for (int rr = 0; rr < 16; ++rr) {
        int dl = rr * 4 + rq;
        xct[(size_t)(cBase + dl) * 8192 + mBase + cl] = T[cl][dl];
    }
}

// ---------------- selective scan on transposed operands ----------------
__global__ __launch_bounds__(256) void scan_k(
    const float* __restrict__ dtt, const float* __restrict__ dblt,
    const float* __restrict__ xct, const float* __restrict__ zst,
    const float* __restrict__ A_log, const float* __restrict__ Dp,
    float* __restrict__ yft)
{
    const int bd = blockIdx.x;
    const int b = bd / DI_, d = bd % DI_;
    const int tid = threadIdx.x;
    const int j = tid >> 4, n = tid & 15;
    const float And = -__expf(A_log[d*16 + n]);
    __shared__ float Ap[16][16], Hl[16][16], Ci[16][17];
    __shared__ float ylds[1024];
    const size_t tb = (size_t)d * 8192 + b * 1024;
    const float* pdt = dtt + tb + j * 64;
    const float* pxc = xct + tb + j * 64;
    const float* pbs = dblt + (size_t)(12 + n) * 8192 + b * 1024 + j * 64;
    const float* pcs = dblt + (size_t)(28 + n) * 8192 + b * 1024 + j * 64;

    float h = 0.f, ap = 1.f;
    for (int i = 0; i < 64; ++i) {
        float dtv = pdt[i];
        float a = __expf(dtv * And);
        h = a * h + dtv * pbs[i] * pxc[i];
        ap *= a;
    }
    Ap[j][n] = ap; Hl[j][n] = h;
    __syncthreads();
    if (tid < 16) {
        float c = 0.f;
        #pragma unroll
        for (int jj = 0; jj < 16; ++jj) {
            Ci[jj][tid] = c;
            c = Ap[jj][tid] * c + Hl[jj][tid];
        }
    }
    __syncthreads();
    h = Ci[j][n];
    const float dp = Dp[d];
    for (int i = 0; i < 64; ++i) {
        float dtv = pdt[i];
        float xcv = pxc[i];
        h = __expf(dtv * And) * h + dtv * pbs[i] * xcv;
        float yv = h * pcs[i];
        yv += __shfl_xor(yv, 1);
        yv += __shfl_xor(yv, 2);
        yv += __shfl_xor(yv, 4);
        yv += __shfl_xor(yv, 8);
        if (n == 0) ylds[j * 64 + i] = yv + xcv * dp;
    }
    __syncthreads();
    {
        float4 y4 = *(float4*)&ylds[tid * 4];
        const float4 z4 = *(const float4*)(zst + tb + tid * 4);
        y4.x *= z4.x; y4.y *= z4.y; y4.z *= z4.z; y4.w *= z4.w;
        *(float4*)(yft + tb + tid * 4) = y4;
    }
}

extern "C" void kernel_launch(void* const* d_in, const int* in_sizes, int n_in,
                              void* d_out, int out_size, void* d_ws, size_t ws_size,
                              hipStream_t stream) {
    const float* x     = (const float*)d_in[0];
    const float* w1    = (const float*)d_in[1];
    const float* g1    = (const float*)d_in[2];
    const float* b1    = (const float*)d_in[3];
    const float* m1    = (const float*)d_in[4];
    const float* v1    = (const float*)d_in[5];
    const float* w2    = (const float*)d_in[6];
    const float* g2    = (const float*)d_in[7];
    const float* b2    = (const float*)d_in[8];
    const float* m2    = (const float*)d_in[9];
    const float* v2    = (const float*)d_in[10];
    const float* in_w  = (const float*)d_in[11];
    const float* cw    = (const float*)d_in[12];
    const float* cb    = (const float*)d_in[13];
    const float* xp_w  = (const float*)d_in[14];
    const float* dt_w  = (const float*)d_in[15];
    const float* dt_b  = (const float*)d_in[16];
    const float* A_log = (const float*)d_in[17];
    const float* Dp    = (const float*)d_in[18];
    const float* out_w = (const float*)d_in[19];
    const float* w3    = (const float*)d_in[20];
    const float* g3    = (const float*)d_in[21];
    const float* b3    = (const float*)d_in[22];
    const float* m3    = (const float*)d_in[23];
    const float* v3    = (const float*)d_in[24];
    const float* w4    = (const float*)d_in[25];
    const float* g4    = (const float*)d_in[26];
    const float* b4    = (const float*)d_in[27];
    const float* m4    = (const float*)d_in[28];
    const float* v4    = (const float*)d_in[29];

    float* ws   = (float*)d_ws;
    float* t1   = ws + O_T1;
    float* t2   = ws + O_T2;
    float* xzb  = ws + O_XZ;
    float* xcb  = ws + O_XC;
    float* dblt = ws + O_DBLT;
    float* xct  = ws + O_XCT;
    float* zst  = ws + O_ZST;
    float* dtt  = ws + O_DTT;   // overlays dead xz (written after xz last use)
    float* yft  = ws + O_YFT;   // overlays dead xz
    float* ub   = ws + O_U;
    u16* Xb4 = (u16*)(ws + O_V);
    u16* Xb1 = Xb4 + (size_t)8192 * 192;
    u16* wt1 = Xb1 + (size_t)8192 * 96;
    u16* wt4 = wt1 + (size_t)9 * 96 * 96;

    // 0) converters
    cvt_w_k<<<64, 256, 0, stream>>>(w1, wt1, 96, 96);
    cvt_w_k<<<192, 256, 0, stream>>>(w4, wt4, 192, 192);
    cvt_x_k<<<3072, 256, 0, stream>>>(x, Xb1);

    // 1) conv3x3 96->96 + BN + GELU (bf16 MFMA) -> t1 f32 NHWC
    conv3x3_mfma_k<96, 96, 32, 0><<<dim3(128, 3), 256, 0, stream>>>(
        Xb1, wt1, g1, b1, m1, v1, t1);

    // 2) 1x1 conv 96->192 + BN + SiLU -> t2 (8192,192)
    gemm_k<EPI_BN_SILU, 0, 0><<<dim3(128, 3), 256, 0, stream>>>(
        8192, 192, 96, 96, t1, w2, t2, g2, b2, m2, v2);

    // 3) in-proj: xz = t2 @ in_w^T  (8192,768)
    gemm_k<EPI_NONE, 0, 0><<<dim3(128, 12), 256, 0, stream>>>(
        8192, 768, 192, 192, t2, in_w, xzb, nullptr, nullptr, nullptr, nullptr);

    // 4a) z-gate: zs_t = silu(z)^T
    ztr_k<<<dim3(128, 6), 256, 0, stream>>>(xzb, zst);

    // 4b) depthwise causal conv + SiLU -> xc row-major + xc_t
    dwconv_k<<<dim3(128, 6), 256, 0, stream>>>(xzb, cw, cb, xcb, xct);

    // 5) x-proj: dbl_t = (xc @ xp_w^T)^T  [44][8192]
    gemm_k<EPI_NONE, 3, 0><<<dim3(128, 1), 256, 0, stream>>>(
        8192, 44, 384, 384, xcb, xp_w, dblt, nullptr, nullptr, nullptr, nullptr);

    // 6) dt_t = softplus(dbl[:, :12] @ dt_w^T + dt_b)^T  [384][8192]  (A transposed)
    gemm_k<EPI_SP, 3, 1><<<dim3(128, 6), 256, 0, stream>>>(
        8192, 384, 12, 8192, dblt, dt_w, dtt, dt_b, nullptr, nullptr, nullptr);

    // 7) selective scan + gate -> yf_t [384][8192]
    scan_k<<<8 * DI_, 256, 0, stream>>>(dtt, dblt, xct, zst, A_log, Dp, yft);

    // 8) out-proj: u = yf @ out_w^T (A transposed)
    gemm_k<EPI_NONE, 0, 1><<<dim3(128, 3), 256, 0, stream>>>(
        8192, 192, 384, 8192, yft, out_w, ub, nullptr, nullptr, nullptr, nullptr);

    // 9) 1x1 conv 192->192 + BN + SiLU -> Xb4 bf16 NHWC
    gemm_k<EPI_BN_SILU, 2, 0><<<dim3(128, 3), 256, 0, stream>>>(
        8192, 192, 192, 192, ub, w3, Xb4, g3, b3, m3, v3);

    // 10) conv3x3 192->192 + BN + GELU (bf16 MFMA) -> out f32 NCHW
    conv3x3_mfma_k<192, 192, 64, 1><<<dim3(128, 3), 256, 0, stream>>>(
        Xb4, wt4, g4, b4, m4, v4, (float*)d_out);
}

// Round 6
// 456.713 us; speedup vs baseline: 1.5962x; 1.5962x over previous
//
#include <hip/hip_runtime.h>
#include <hip/hip_bf16.h>

using u16 = unsigned short;
using short8 = __attribute__((ext_vector_type(8))) short;
using f32x4  = __attribute__((ext_vector_type(4))) float;

constexpr int INC_ = 96;
constexpr int D_   = 192;
constexpr int DI_  = 384;

// workspace offsets in floats
constexpr size_t O_T1   = 0;                        // 8192*96   t1 (f32 NHWC)
constexpr size_t O_T2   = O_T1 + (size_t)8192*96;   // 8192*192  t2
constexpr size_t O_XZ   = O_T2 + (size_t)8192*192;  // 8192*768  xz; later dt_t+yf_t
constexpr size_t O_XC   = O_XZ + (size_t)8192*768;  // 8192*384  xc row-major
constexpr size_t O_DBLT = O_XC + (size_t)8192*384;  // 44*8192   dbl transposed
constexpr size_t O_XCT  = O_DBLT + (size_t)44*8192; // 384*8192  xc transposed
constexpr size_t O_ZST  = O_XCT + (size_t)384*8192; // 384*8192  silu(z) transposed
constexpr size_t O_U    = O_ZST + (size_t)384*8192; // 8192*192  u
constexpr size_t O_V    = O_U  + (size_t)8192*192;  // bf16 arena
constexpr size_t O_DTT  = O_XZ;                     // overlays dead xz
constexpr size_t O_YFT  = O_XZ + (size_t)384*8192;  // overlays dead xz

__device__ __forceinline__ u16 f2b(float f) {
    __hip_bfloat16 h = __float2bfloat16(f);
    return *reinterpret_cast<u16*>(&h);
}

// ---------------- weight transform: [CO][CI][3][3] f32 -> [9][CO][CI] bf16 ----------------
__global__ __launch_bounds__(256) void cvt_w_k(
    const float* __restrict__ src, u16* __restrict__ dst, int CO, int CI)
{
    int total = 9 * CO * CI;
    for (int idx = blockIdx.x * 256 + threadIdx.x; idx < total; idx += gridDim.x * 256) {
        int ci = idx % CI;
        int rem = idx / CI;
        int co = rem % CO;
        int t = rem / CO;
        dst[idx] = f2b(src[((size_t)co * CI + ci) * 9 + t]);
    }
}

// ---------------- x: NCHW f32 -> NHWC bf16 ----------------
__global__ __launch_bounds__(256) void cvt_x_k(
    const float* __restrict__ src, u16* __restrict__ dst)
{
    int idx = blockIdx.x * 256 + threadIdx.x;   // 8192*96
    int ci = idx % 96;
    int px = idx / 96;
    dst[idx] = f2b(src[(((size_t)(px >> 10) * 96 + ci) << 10) | (size_t)(px & 1023)]);
}

// ---------------- 3x3 conv as bf16-MFMA shift-GEMM + BN + exact GELU ----------------
template<int CIN, int COUT, int NTILE, int OUTM>
__global__ __launch_bounds__(256) void conv3x3_mfma_k(
    const u16* __restrict__ Xb, const u16* __restrict__ Wt,
    const float* __restrict__ g, const float* __restrict__ b,
    const float* __restrict__ m, const float* __restrict__ v,
    float* __restrict__ out)
{
    constexpr int LDA = 40;
    constexpr int NT = NTILE / 16;
    __shared__ u16 As[64 * LDA];
    __shared__ u16 Bs[NTILE * LDA];
    const int tid = threadIdx.x;
    const int wave = tid >> 6, lane = tid & 63;
    const int quad = lane >> 4, l16 = lane & 15;
    const int rowBase = blockIdx.x * 64;
    const int colBase = blockIdx.y * NTILE;

    f32x4 acc[NT];
    #pragma unroll
    for (int nt = 0; nt < NT; ++nt)
        #pragma unroll
        for (int i = 0; i < 4; ++i) acc[nt][i] = 0.f;

    const int ar = tid >> 2, aseg = tid & 3;
    const int apx = rowBase + ar;
    const int ah = (apx >> 5) & 31, aw = apx & 31;

    for (int t = 0; t < 9; ++t) {
        const int dr = t / 3 - 1, dc = t % 3 - 1;
        const bool avalid = ((unsigned)(ah + dr) < 32u) && ((unsigned)(aw + dc) < 32u);
        const int apxs = apx + dr * 32 + dc;
        for (int ci0 = 0; ci0 < CIN; ci0 += 32) {
            __syncthreads();
            uint4 va = make_uint4(0u, 0u, 0u, 0u);
            if (avalid)
                va = *(const uint4*)(Xb + (size_t)apxs * CIN + ci0 + aseg * 8);
            *(uint4*)(As + ar * LDA + aseg * 8) = va;
            if (tid < NTILE * 4) {
                int r = tid >> 2, seg = tid & 3;
                uint4 vb = *(const uint4*)(Wt + ((size_t)t * COUT + colBase + r) * CIN + ci0 + seg * 8);
                *(uint4*)(Bs + r * LDA + seg * 8) = vb;
            }
            __syncthreads();
            short8 a = *(const short8*)(As + (wave * 16 + l16) * LDA + quad * 8);
            #pragma unroll
            for (int nt = 0; nt < NT; ++nt) {
                short8 bf = *(const short8*)(Bs + (nt * 16 + l16) * LDA + quad * 8);
                acc[nt] = __builtin_amdgcn_mfma_f32_16x16x32_bf16(a, bf, acc[nt], 0, 0, 0);
            }
        }
    }

    const int px0 = rowBase + wave * 16 + quad * 4;
    #pragma unroll
    for (int nt = 0; nt < NT; ++nt) {
        const int co = colBase + nt * 16 + l16;
        const float sc = g[co] * rsqrtf(v[co] + 1e-5f);
        const float bb = b[co] - m[co] * sc;
        float o[4];
        #pragma unroll
        for (int r = 0; r < 4; ++r) {
            float xv = acc[nt][r] * sc + bb;
            o[r] = 0.5f * xv * (1.f + erff(xv * 0.70710678f));
        }
        if (OUTM == 0) {
            #pragma unroll
            for (int r = 0; r < 4; ++r)
                out[(size_t)(px0 + r) * COUT + co] = o[r];
        } else {
            const int img = px0 >> 10, off = px0 & 1023;
            *(float4*)(out + (((size_t)img * COUT + co) << 10) + off) =
                make_float4(o[0], o[1], o[2], o[3]);
        }
    }
}

// ---------------- generic tiled f32 GEMM: C[M,N] = A[M,K] @ B[N,K]^T ----------------
enum { EPI_NONE = 0, EPI_BN_SILU = 1, EPI_SP = 2 };

template<int EPI, int OUTM, int ATRANS>
__global__ __launch_bounds__(256) void gemm_k(
    int M, int N, int K, int lda,
    const float* __restrict__ A, const float* __restrict__ B, void* __restrict__ C,
    const float* __restrict__ p0, const float* __restrict__ p1,
    const float* __restrict__ p2, const float* __restrict__ p3)
{
    __shared__ float As[16][68];
    __shared__ float Bs[16][68];
    const int tid = threadIdx.x;
    const int tx = tid & 15, ty = tid >> 4;
    const int rowBase = blockIdx.x * 64;
    const int colBase = blockIdx.y * 64;
    const int lr = tid >> 2;
    const int kq = (tid & 3) << 2;
    float acc[4][4] = {};
    for (int kt = 0; kt < K; kt += 16) {
        float4 bv = make_float4(0.f, 0.f, 0.f, 0.f);
        int bn = colBase + lr;
        if (bn < N && kt + kq < K)
            bv = *(const float4*)(B + (size_t)bn * K + kt + kq);
        if (ATRANS) {
            const int kk = tid >> 4, seg = tid & 15;
            float4 av = *(const float4*)(A + (size_t)(kt + kk) * lda + rowBase + seg * 4);
            *(float4*)&As[kk][seg * 4] = av;
        } else {
            float4 av = make_float4(0.f, 0.f, 0.f, 0.f);
            if (kt + kq < K)
                av = *(const float4*)(A + (size_t)(rowBase + lr) * lda + kt + kq);
            As[kq+0][lr] = av.x; As[kq+1][lr] = av.y; As[kq+2][lr] = av.z; As[kq+3][lr] = av.w;
        }
        Bs[kq+0][lr] = bv.x; Bs[kq+1][lr] = bv.y; Bs[kq+2][lr] = bv.z; Bs[kq+3][lr] = bv.w;
        __syncthreads();
        #pragma unroll
        for (int kk = 0; kk < 16; ++kk) {
            float4 a = *(const float4*)&As[kk][ty << 2];
            float4 b = *(const float4*)&Bs[kk][tx << 2];
            float ar[4] = {a.x, a.y, a.z, a.w};
            float br[4] = {b.x, b.y, b.z, b.w};
            #pragma unroll
            for (int i = 0; i < 4; ++i)
                #pragma unroll
                for (int jj = 0; jj < 4; ++jj)
                    acc[i][jj] += ar[i] * br[jj];
        }
        __syncthreads();
    }
    #pragma unroll
    for (int jj = 0; jj < 4; ++jj) {
        int col = colBase + (tx << 2) + jj;
        if (col >= N) continue;
        float sc = 0.f, bb = 0.f;
        if (EPI == EPI_BN_SILU) {
            sc = p0[col] * rsqrtf(p3[col] + 1e-5f);
            bb = p1[col] - p2[col] * sc;
        } else if (EPI == EPI_SP) {
            bb = p0[col];
        }
        float o[4];
        #pragma unroll
        for (int i = 0; i < 4; ++i) {
            float xv = acc[i][jj];
            if (EPI == EPI_BN_SILU) {
                xv = xv * sc + bb;
                xv = xv / (1.f + __expf(-xv));
            } else if (EPI == EPI_SP) {
                xv += bb;
                xv = (xv > 20.f) ? xv : log1pf(__expf(xv));
            }
            o[i] = xv;
        }
        if (OUTM == 3) {
            *(float4*)((float*)C + (size_t)col * M + rowBase + (ty << 2)) =
                make_float4(o[0], o[1], o[2], o[3]);
        } else {
            #pragma unroll
            for (int i = 0; i < 4; ++i) {
                size_t idx = (size_t)(rowBase + (ty << 2) + i) * N + col;
                if (OUTM == 2) ((u16*)C)[idx] = f2b(o[i]);
                else           ((float*)C)[idx] = o[i];
            }
        }
    }
}

// ---------------- z-gate extract: zs_t[d][m] = silu(xz[m][384+d]) ----------------
__global__ __launch_bounds__(256) void ztr_k(
    const float* __restrict__ xz, float* __restrict__ zst)
{
    __shared__ float T[64][65];
    const int tid = threadIdx.x;
    const int cl = tid & 63, rq = tid >> 6;
    const int mBase = blockIdx.x * 64, dBase = blockIdx.y * 64;
    #pragma unroll
    for (int rr = 0; rr < 16; ++rr) {
        int ml = rr * 4 + rq;
        float zv = xz[(size_t)(mBase + ml) * 768 + 384 + dBase + cl];
        T[ml][cl] = zv / (1.f + __expf(-zv));
    }
    __syncthreads();
    #pragma unroll
    for (int rr = 0; rr < 16; ++rr) {
        int dl = rr * 4 + rq;
        zst[(size_t)(dBase + dl) * 8192 + mBase + cl] = T[cl][dl];
    }
}

// ---------------- depthwise causal conv (K=4) + SiLU, dual-layout output ----------------
__global__ __launch_bounds__(256) void dwconv_k(
    const float* __restrict__ xz, const float* __restrict__ cw, const float* __restrict__ cb,
    float* __restrict__ xc, float* __restrict__ xct)
{
    __shared__ float T[64][65];
    const int tid = threadIdx.x;
    const int cl = tid & 63, rq = tid >> 6;
    const int mBase = blockIdx.x * 64, cBase = blockIdx.y * 64;
    const int c = cBase + cl;
    const float w0 = cw[c*4+0], w1 = cw[c*4+1], w2 = cw[c*4+2], w3 = cw[c*4+3];
    const float bias = cb[c];
    #pragma unroll
    for (int rr = 0; rr < 16; ++rr) {
        int ml = rr * 4 + rq;
        int bl = mBase + ml;
        int l = bl & 1023;
        float acc = bias + xz[(size_t)bl * 768 + c] * w3;
        if (l >= 1) acc += xz[(size_t)(bl-1) * 768 + c] * w2;
        if (l >= 2) acc += xz[(size_t)(bl-2) * 768 + c] * w1;
        if (l >= 3) acc += xz[(size_t)(bl-3) * 768 + c] * w0;
        float s = acc / (1.f + __expf(-acc));
        xc[(size_t)bl * DI_ + c] = s;
        T[ml][cl] = s;
    }
    __syncthreads();
    #pragma unroll
    for (int rr = 0; rr < 16; ++rr) {
        int dl = rr * 4 + rq;
        xct[(size_t)(cBase + dl) * 8192 + mBase + cl] = T[cl][dl];
    }
}

// ---------------- selective scan: thread = 4 timesteps, all 16 states in regs ----------------
// All global accesses are block-contiguous float4. Chunk combine via 64-lane
// shfl_up scan of (a,h) -> (a1*a2, a2*h1 + h2), plus tiny LDS cross-wave stage.
__global__ __launch_bounds__(256) void scan_k(
    const float* __restrict__ dtt, const float* __restrict__ dblt,
    const float* __restrict__ xct, const float* __restrict__ zst,
    const float* __restrict__ A_log, const float* __restrict__ Dp,
    float* __restrict__ yft)
{
    const int bd = blockIdx.x;
    const int b = bd / DI_, d = bd % DI_;
    const int tid = threadIdx.x;
    const int lane = tid & 63, wave = tid >> 6;
    const size_t tb = (size_t)d * 8192 + (size_t)b * 1024;
    const size_t nb = (size_t)b * 1024;
    const int t4 = tid * 4;

    const float4 dt4 = *(const float4*)(dtt + tb + t4);
    const float4 xc4 = *(const float4*)(xct + tb + t4);
    const float dtxc[4] = {dt4.x*xc4.x, dt4.y*xc4.y, dt4.z*xc4.z, dt4.w*xc4.w};

    float And[16];
    #pragma unroll
    for (int n = 0; n < 16; ++n) And[n] = -__expf(A_log[d*16 + n]);

    // pass 1: per-n local chunk scan (h_in = 0)
    float ap[16], hl[16];
    #pragma unroll
    for (int n = 0; n < 16; ++n) {
        const float4 bs4 = *(const float4*)(dblt + (size_t)(12 + n) * 8192 + nb + t4);
        float a = __expf(dt4.x * And[n]);
        float h = dtxc[0] * bs4.x;
        float apn = a;
        a = __expf(dt4.y * And[n]); h = a*h + dtxc[1]*bs4.y; apn *= a;
        a = __expf(dt4.z * And[n]); h = a*h + dtxc[2]*bs4.z; apn *= a;
        a = __expf(dt4.w * And[n]); h = a*h + dtxc[3]*bs4.w; apn *= a;
        ap[n] = apn; hl[n] = h;
    }

    // inclusive 64-lane scan per n
    #pragma unroll
    for (int dlt = 1; dlt < 64; dlt <<= 1) {
        #pragma unroll
        for (int n = 0; n < 16; ++n) {
            float au = __shfl_up(ap[n], dlt, 64);
            float hu = __shfl_up(hl[n], dlt, 64);
            if (lane >= dlt) {
                hl[n] = ap[n] * hu + hl[n];
                ap[n] = ap[n] * au;
            }
        }
    }

    // wave totals (inclusive lane 63) -> LDS
    __shared__ float wA[4][16], wH[4][16];
    if (lane == 63) {
        #pragma unroll
        for (int n = 0; n < 16; ++n) { wA[wave][n] = ap[n]; wH[wave][n] = hl[n]; }
    }
    __syncthreads();

    // in-place exclusive shift within wave
    #pragma unroll
    for (int n = 0; n < 16; ++n) {
        float au = __shfl_up(ap[n], 1, 64);
        float hu = __shfl_up(hl[n], 1, 64);
        ap[n] = (lane == 0) ? 1.f : au;
        hl[n] = (lane == 0) ? 0.f : hu;
    }

    // pass 2: recompute with corrected h_in, fuse y-reduce + Dp + z-gate
    float y0 = 0.f, y1 = 0.f, y2 = 0.f, y3 = 0.f;
    #pragma unroll
    for (int n = 0; n < 16; ++n) {
        float Hwp = 0.f;
        for (int w = 0; w < wave; ++w) Hwp = wA[w][n] * Hwp + wH[w][n];
        float h = ap[n] * Hwp + hl[n];
        const float4 bs4 = *(const float4*)(dblt + (size_t)(12 + n) * 8192 + nb + t4);
        const float4 cs4 = *(const float4*)(dblt + (size_t)(28 + n) * 8192 + nb + t4);
        float a;
        a = __expf(dt4.x * And[n]); h = a*h + dtxc[0]*bs4.x; y0 += h * cs4.x;
        a = __expf(dt4.y * And[n]); h = a*h + dtxc[1]*bs4.y; y1 += h * cs4.y;
        a = __expf(dt4.z * And[n]); h = a*h + dtxc[2]*bs4.z; y2 += h * cs4.z;
        a = __expf(dt4.w * And[n]); h = a*h + dtxc[3]*bs4.w; y3 += h * cs4.w;
    }
    const float dp = Dp[d];
    const float4 zs4 = *(const float4*)(zst + tb + t4);
    float4 o;
    o.x = (y0 + xc4.x * dp) * zs4.x;
    o.y = (y1 + xc4.y * dp) * zs4.y;
    o.z = (y2 + xc4.z * dp) * zs4.z;
    o.w = (y3 + xc4.w * dp) * zs4.w;
    *(float4*)(yft + tb + t4) = o;
}

extern "C" void kernel_launch(void* const* d_in, const int* in_sizes, int n_in,
                              void* d_out, int out_size, void* d_ws, size_t ws_size,
                              hipStream_t stream) {
    const float* x     = (const float*)d_in[0];
    const float* w1    = (const float*)d_in[1];
    const float* g1    = (const float*)d_in[2];
    const float* b1    = (const float*)d_in[3];
    const float* m1    = (const float*)d_in[4];
    const float* v1    = (const float*)d_in[5];
    const float* w2    = (const float*)d_in[6];
    const float* g2    = (const float*)d_in[7];
    const float* b2    = (const float*)d_in[8];
    const float* m2    = (const float*)d_in[9];
    const float* v2    = (const float*)d_in[10];
    const float* in_w  = (const float*)d_in[11];
    const float* cw    = (const float*)d_in[12];
    const float* cb    = (const float*)d_in[13];
    const float* xp_w  = (const float*)d_in[14];
    const float* dt_w  = (const float*)d_in[15];
    const float* dt_b  = (const float*)d_in[16];
    const float* A_log = (const float*)d_in[17];
    const float* Dp    = (const float*)d_in[18];
    const float* out_w = (const float*)d_in[19];
    const float* w3    = (const float*)d_in[20];
    const float* g3    = (const float*)d_in[21];
    const float* b3    = (const float*)d_in[22];
    const float* m3    = (const float*)d_in[23];
    const float* v3    = (const float*)d_in[24];
    const float* w4    = (const float*)d_in[25];
    const float* g4    = (const float*)d_in[26];
    const float* b4    = (const float*)d_in[27];
    const float* m4    = (const float*)d_in[28];
    const float* v4    = (const float*)d_in[29];

    float* ws   = (float*)d_ws;
    float* t1   = ws + O_T1;
    float* t2   = ws + O_T2;
    float* xzb  = ws + O_XZ;
    float* xcb  = ws + O_XC;
    float* dblt = ws + O_DBLT;
    float* xct  = ws + O_XCT;
    float* zst  = ws + O_ZST;
    float* dtt  = ws + O_DTT;
    float* yft  = ws + O_YFT;
    float* ub   = ws + O_U;
    u16* Xb4 = (u16*)(ws + O_V);
    u16* Xb1 = Xb4 + (size_t)8192 * 192;
    u16* wt1 = Xb1 + (size_t)8192 * 96;
    u16* wt4 = wt1 + (size_t)9 * 96 * 96;

    // 0) converters
    cvt_w_k<<<64, 256, 0, stream>>>(w1, wt1, 96, 96);
    cvt_w_k<<<192, 256, 0, stream>>>(w4, wt4, 192, 192);
    cvt_x_k<<<3072, 256, 0, stream>>>(x, Xb1);

    // 1) conv3x3 96->96 + BN + GELU (bf16 MFMA) -> t1 f32 NHWC
    conv3x3_mfma_k<96, 96, 32, 0><<<dim3(128, 3), 256, 0, stream>>>(
        Xb1, wt1, g1, b1, m1, v1, t1);

    // 2) 1x1 conv 96->192 + BN + SiLU -> t2 (8192,192)
    gemm_k<EPI_BN_SILU, 0, 0><<<dim3(128, 3), 256, 0, stream>>>(
        8192, 192, 96, 96, t1, w2, t2, g2, b2, m2, v2);

    // 3) in-proj: xz = t2 @ in_w^T  (8192,768)
    gemm_k<EPI_NONE, 0, 0><<<dim3(128, 12), 256, 0, stream>>>(
        8192, 768, 192, 192, t2, in_w, xzb, nullptr, nullptr, nullptr, nullptr);

    // 4a) z-gate: zs_t = silu(z)^T
    ztr_k<<<dim3(128, 6), 256, 0, stream>>>(xzb, zst);

    // 4b) depthwise causal conv + SiLU -> xc row-major + xc_t
    dwconv_k<<<dim3(128, 6), 256, 0, stream>>>(xzb, cw, cb, xcb, xct);

    // 5) x-proj: dbl_t = (xc @ xp_w^T)^T  [44][8192]
    gemm_k<EPI_NONE, 3, 0><<<dim3(128, 1), 256, 0, stream>>>(
        8192, 44, 384, 384, xcb, xp_w, dblt, nullptr, nullptr, nullptr, nullptr);

    // 6) dt_t = softplus(dbl[:, :12] @ dt_w^T + dt_b)^T  [384][8192]
    gemm_k<EPI_SP, 3, 1><<<dim3(128, 6), 256, 0, stream>>>(
        8192, 384, 12, 8192, dblt, dt_w, dtt, dt_b, nullptr, nullptr, nullptr);

    // 7) selective scan + gate -> yf_t [384][8192]
    scan_k<<<8 * DI_, 256, 0, stream>>>(dtt, dblt, xct, zst, A_log, Dp, yft);

    // 8) out-proj: u = yf @ out_w^T (A transposed)
    gemm_k<EPI_NONE, 0, 1><<<dim3(128, 3), 256, 0, stream>>>(
        8192, 192, 384, 8192, yft, out_w, ub, nullptr, nullptr, nullptr, nullptr);

    // 9) 1x1 conv 192->192 + BN + SiLU -> Xb4 bf16 NHWC
    gemm_k<EPI_BN_SILU, 2, 0><<<dim3(128, 3), 256, 0, stream>>>(
        8192, 192, 192, 192, ub, w3, Xb4, g3, b3, m3, v3);

    // 10) conv3x3 192->192 + BN + GELU (bf16 MFMA) -> out f32 NCHW
    conv3x3_mfma_k<192, 192, 64, 1><<<dim3(128, 3), 256, 0, stream>>>(
        Xb4, wt4, g4, b4, m4, v4, (float*)d_out);
}

// Round 7
// 326.249 us; speedup vs baseline: 2.2344x; 1.3999x over previous
//
#include <hip/hip_runtime.h>
#include <hip/hip_bf16.h>

using u16 = unsigned short;
using short8 = __attribute__((ext_vector_type(8))) short;
using f32x4  = __attribute__((ext_vector_type(4))) float;

constexpr int INC_ = 96;
constexpr int D_   = 192;
constexpr int DI_  = 384;

// workspace offsets in floats
constexpr size_t O_T1   = 0;                        // 8192*96   t1 (f32 NHWC)
constexpr size_t O_T2   = O_T1 + (size_t)8192*96;   // 8192*192  -> now bf16 t2 + bf16 in_w
constexpr size_t O_XZ   = O_T2 + (size_t)8192*192;  // 8192*768  xz; later dt_t+yf_t
constexpr size_t O_XC   = O_XZ + (size_t)8192*768;  // 8192*384  xc row-major
constexpr size_t O_DBLT = O_XC + (size_t)8192*384;  // 44*8192   dbl transposed
constexpr size_t O_XCT  = O_DBLT + (size_t)44*8192; // 384*8192  xc transposed
constexpr size_t O_ZST  = O_XCT + (size_t)384*8192; // 384*8192  silu(z) transposed
constexpr size_t O_U    = O_ZST + (size_t)384*8192; // 8192*192  u
constexpr size_t O_V    = O_U  + (size_t)8192*192;  // bf16 arena
constexpr size_t O_DTT  = O_XZ;                     // overlays dead xz
constexpr size_t O_YFT  = O_XZ + (size_t)384*8192;  // overlays dead xz

__device__ __forceinline__ u16 f2b(float f) {
    __hip_bfloat16 h = __float2bfloat16(f);
    return *reinterpret_cast<u16*>(&h);
}

// ---------------- generic elementwise f32 -> bf16 ----------------
__global__ __launch_bounds__(256) void cvt_e_k(
    const float* __restrict__ src, u16* __restrict__ dst, int n)
{
    for (int i = blockIdx.x * 256 + threadIdx.x; i < n; i += gridDim.x * 256)
        dst[i] = f2b(src[i]);
}

// ---------------- weight transform: [CO][CI][3][3] f32 -> [9][CO][CI] bf16 ----------------
__global__ __launch_bounds__(256) void cvt_w_k(
    const float* __restrict__ src, u16* __restrict__ dst, int CO, int CI)
{
    int total = 9 * CO * CI;
    for (int idx = blockIdx.x * 256 + threadIdx.x; idx < total; idx += gridDim.x * 256) {
        int ci = idx % CI;
        int rem = idx / CI;
        int co = rem % CO;
        int t = rem / CO;
        dst[idx] = f2b(src[((size_t)co * CI + ci) * 9 + t]);
    }
}

// ---------------- x: NCHW f32 -> NHWC bf16 ----------------
__global__ __launch_bounds__(256) void cvt_x_k(
    const float* __restrict__ src, u16* __restrict__ dst)
{
    int idx = blockIdx.x * 256 + threadIdx.x;   // 8192*96
    int ci = idx % 96;
    int px = idx / 96;
    dst[idx] = f2b(src[(((size_t)(px >> 10) * 96 + ci) << 10) | (size_t)(px & 1023)]);
}

// ---------------- 3x3 conv as bf16-MFMA shift-GEMM + BN + exact GELU ----------------
template<int CIN, int COUT, int NTILE, int OUTM>
__global__ __launch_bounds__(256) void conv3x3_mfma_k(
    const u16* __restrict__ Xb, const u16* __restrict__ Wt,
    const float* __restrict__ g, const float* __restrict__ b,
    const float* __restrict__ m, const float* __restrict__ v,
    float* __restrict__ out)
{
    constexpr int LDA = 40;
    constexpr int NT = NTILE / 16;
    __shared__ u16 As[64 * LDA];
    __shared__ u16 Bs[NTILE * LDA];
    const int tid = threadIdx.x;
    const int wave = tid >> 6, lane = tid & 63;
    const int quad = lane >> 4, l16 = lane & 15;
    const int rowBase = blockIdx.x * 64;
    const int colBase = blockIdx.y * NTILE;

    f32x4 acc[NT];
    #pragma unroll
    for (int nt = 0; nt < NT; ++nt)
        #pragma unroll
        for (int i = 0; i < 4; ++i) acc[nt][i] = 0.f;

    const int ar = tid >> 2, aseg = tid & 3;
    const int apx = rowBase + ar;
    const int ah = (apx >> 5) & 31, aw = apx & 31;

    for (int t = 0; t < 9; ++t) {
        const int dr = t / 3 - 1, dc = t % 3 - 1;
        const bool avalid = ((unsigned)(ah + dr) < 32u) && ((unsigned)(aw + dc) < 32u);
        const int apxs = apx + dr * 32 + dc;
        for (int ci0 = 0; ci0 < CIN; ci0 += 32) {
            __syncthreads();
            uint4 va = make_uint4(0u, 0u, 0u, 0u);
            if (avalid)
                va = *(const uint4*)(Xb + (size_t)apxs * CIN + ci0 + aseg * 8);
            *(uint4*)(As + ar * LDA + aseg * 8) = va;
            if (tid < NTILE * 4) {
                int r = tid >> 2, seg = tid & 3;
                uint4 vb = *(const uint4*)(Wt + ((size_t)t * COUT + colBase + r) * CIN + ci0 + seg * 8);
                *(uint4*)(Bs + r * LDA + seg * 8) = vb;
            }
            __syncthreads();
            short8 a = *(const short8*)(As + (wave * 16 + l16) * LDA + quad * 8);
            #pragma unroll
            for (int nt = 0; nt < NT; ++nt) {
                short8 bf = *(const short8*)(Bs + (nt * 16 + l16) * LDA + quad * 8);
                acc[nt] = __builtin_amdgcn_mfma_f32_16x16x32_bf16(a, bf, acc[nt], 0, 0, 0);
            }
        }
    }

    const int px0 = rowBase + wave * 16 + quad * 4;
    #pragma unroll
    for (int nt = 0; nt < NT; ++nt) {
        const int co = colBase + nt * 16 + l16;
        const float sc = g[co] * rsqrtf(v[co] + 1e-5f);
        const float bb = b[co] - m[co] * sc;
        float o[4];
        #pragma unroll
        for (int r = 0; r < 4; ++r) {
            float xv = acc[nt][r] * sc + bb;
            o[r] = 0.5f * xv * (1.f + erff(xv * 0.70710678f));
        }
        if (OUTM == 0) {
            #pragma unroll
            for (int r = 0; r < 4; ++r)
                out[(size_t)(px0 + r) * COUT + co] = o[r];
        } else {
            const int img = px0 >> 10, off = px0 & 1023;
            *(float4*)(out + (((size_t)img * COUT + co) << 10) + off) =
                make_float4(o[0], o[1], o[2], o[3]);
        }
    }
}

// ---------------- bf16 MFMA GEMM: C[M,N] = A[M,K] @ B[N,K]^T (f32 out) ----------------
// A, B bf16 row-major with K contiguous. K % 32 == 0, N % NTILE == 0, M % 64 == 0.
template<int NTILE>
__global__ __launch_bounds__(256) void gemm_mfma_k(
    int M, int N, int K,
    const u16* __restrict__ Ab, const u16* __restrict__ Bb, float* __restrict__ C)
{
    constexpr int LDA = 40;
    constexpr int NT = NTILE / 16;
    __shared__ u16 As[64 * LDA];
    __shared__ u16 Bs[NTILE * LDA];
    const int tid = threadIdx.x;
    const int wave = tid >> 6, lane = tid & 63;
    const int quad = lane >> 4, l16 = lane & 15;
    const int rowBase = blockIdx.x * 64;
    const int colBase = blockIdx.y * NTILE;

    f32x4 acc[NT];
    #pragma unroll
    for (int nt = 0; nt < NT; ++nt)
        #pragma unroll
        for (int i = 0; i < 4; ++i) acc[nt][i] = 0.f;

    const int ar = tid >> 2, aseg = tid & 3;

    for (int k0 = 0; k0 < K; k0 += 32) {
        __syncthreads();
        uint4 va = *(const uint4*)(Ab + (size_t)(rowBase + ar) * K + k0 + aseg * 8);
        *(uint4*)(As + ar * LDA + aseg * 8) = va;
        if (tid < NTILE * 4) {
            int r = tid >> 2, seg = tid & 3;
            uint4 vb = *(const uint4*)(Bb + (size_t)(colBase + r) * K + k0 + seg * 8);
            *(uint4*)(Bs + r * LDA + seg * 8) = vb;
        }
        __syncthreads();
        short8 a = *(const short8*)(As + (wave * 16 + l16) * LDA + quad * 8);
        #pragma unroll
        for (int nt = 0; nt < NT; ++nt) {
            short8 bf = *(const short8*)(Bs + (nt * 16 + l16) * LDA + quad * 8);
            acc[nt] = __builtin_amdgcn_mfma_f32_16x16x32_bf16(a, bf, acc[nt], 0, 0, 0);
        }
    }

    const int px0 = rowBase + wave * 16 + quad * 4;
    #pragma unroll
    for (int nt = 0; nt < NT; ++nt) {
        const int co = colBase + nt * 16 + l16;
        #pragma unroll
        for (int r = 0; r < 4; ++r)
            C[(size_t)(px0 + r) * N + co] = acc[nt][r];
    }
}

// ---------------- generic tiled f32 GEMM: C[M,N] = A[M,K] @ B[N,K]^T ----------------
enum { EPI_NONE = 0, EPI_BN_SILU = 1, EPI_SP = 2 };

template<int EPI, int OUTM, int ATRANS>
__global__ __launch_bounds__(256) void gemm_k(
    int M, int N, int K, int lda,
    const float* __restrict__ A, const float* __restrict__ B, void* __restrict__ C,
    const float* __restrict__ p0, const float* __restrict__ p1,
    const float* __restrict__ p2, const float* __restrict__ p3)
{
    __shared__ float As[16][68];
    __shared__ float Bs[16][68];
    const int tid = threadIdx.x;
    const int tx = tid & 15, ty = tid >> 4;
    const int rowBase = blockIdx.x * 64;
    const int colBase = blockIdx.y * 64;
    const int lr = tid >> 2;
    const int kq = (tid & 3) << 2;
    float acc[4][4] = {};
    for (int kt = 0; kt < K; kt += 16) {
        float4 bv = make_float4(0.f, 0.f, 0.f, 0.f);
        int bn = colBase + lr;
        if (bn < N && kt + kq < K)
            bv = *(const float4*)(B + (size_t)bn * K + kt + kq);
        if (ATRANS) {
            const int kk = tid >> 4, seg = tid & 15;
            float4 av = *(const float4*)(A + (size_t)(kt + kk) * lda + rowBase + seg * 4);
            *(float4*)&As[kk][seg * 4] = av;
        } else {
            float4 av = make_float4(0.f, 0.f, 0.f, 0.f);
            if (kt + kq < K)
                av = *(const float4*)(A + (size_t)(rowBase + lr) * lda + kt + kq);
            As[kq+0][lr] = av.x; As[kq+1][lr] = av.y; As[kq+2][lr] = av.z; As[kq+3][lr] = av.w;
        }
        Bs[kq+0][lr] = bv.x; Bs[kq+1][lr] = bv.y; Bs[kq+2][lr] = bv.z; Bs[kq+3][lr] = bv.w;
        __syncthreads();
        #pragma unroll
        for (int kk = 0; kk < 16; ++kk) {
            float4 a = *(const float4*)&As[kk][ty << 2];
            float4 b = *(const float4*)&Bs[kk][tx << 2];
            float ar[4] = {a.x, a.y, a.z, a.w};
            float br[4] = {b.x, b.y, b.z, b.w};
            #pragma unroll
            for (int i = 0; i < 4; ++i)
                #pragma unroll
                for (int jj = 0; jj < 4; ++jj)
                    acc[i][jj] += ar[i] * br[jj];
        }
        __syncthreads();
    }
    #pragma unroll
    for (int jj = 0; jj < 4; ++jj) {
        int col = colBase + (tx << 2) + jj;
        if (col >= N) continue;
        float sc = 0.f, bb = 0.f;
        if (EPI == EPI_BN_SILU) {
            sc = p0[col] * rsqrtf(p3[col] + 1e-5f);
            bb = p1[col] - p2[col] * sc;
        } else if (EPI == EPI_SP) {
            bb = p0[col];
        }
        float o[4];
        #pragma unroll
        for (int i = 0; i < 4; ++i) {
            float xv = acc[i][jj];
            if (EPI == EPI_BN_SILU) {
                xv = xv * sc + bb;
                xv = xv / (1.f + __expf(-xv));
            } else if (EPI == EPI_SP) {
                xv += bb;
                xv = (xv > 20.f) ? xv : log1pf(__expf(xv));
            }
            o[i] = xv;
        }
        if (OUTM == 3) {
            *(float4*)((float*)C + (size_t)col * M + rowBase + (ty << 2)) =
                make_float4(o[0], o[1], o[2], o[3]);
        } else {
            #pragma unroll
            for (int i = 0; i < 4; ++i) {
                size_t idx = (size_t)(rowBase + (ty << 2) + i) * N + col;
                if (OUTM == 2) ((u16*)C)[idx] = f2b(o[i]);
                else           ((float*)C)[idx] = o[i];
            }
        }
    }
}

// ---------------- z-gate extract: zs_t[d][m] = silu(xz[m][384+d]) ----------------
__global__ __launch_bounds__(256) void ztr_k(
    const float* __restrict__ xz, float* __restrict__ zst)
{
    __shared__ float T[64][65];
    const int tid = threadIdx.x;
    const int cl = tid & 63, rq = tid >> 6;
    const int mBase = blockIdx.x * 64, dBase = blockIdx.y * 64;
    #pragma unroll
    for (int rr = 0; rr < 16; ++rr) {
        int ml = rr * 4 + rq;
        float zv = xz[(size_t)(mBase + ml) * 768 + 384 + dBase + cl];
        T[ml][cl] = zv / (1.f + __expf(-zv));
    }
    __syncthreads();
    #pragma unroll
    for (int rr = 0; rr < 16; ++rr) {
        int dl = rr * 4 + rq;
        zst[(size_t)(dBase + dl) * 8192 + mBase + cl] = T[cl][dl];
    }
}

// ---------------- depthwise causal conv (K=4) + SiLU, dual-layout output ----------------
__global__ __launch_bounds__(256) void dwconv_k(
    const float* __restrict__ xz, const float* __restrict__ cw, const float* __restrict__ cb,
    float* __restrict__ xc, float* __restrict__ xct)
{
    __shared__ float T[64][65];
    const int tid = threadIdx.x;
    const int cl = tid & 63, rq = tid >> 6;
    const int mBase = blockIdx.x * 64, cBase = blockIdx.y * 64;
    const int c = cBase + cl;
    const float w0 = cw[c*4+0], w1 = cw[c*4+1], w2 = cw[c*4+2], w3 = cw[c*4+3];
    const float bias = cb[c];
    #pragma unroll
    for (int rr = 0; rr < 16; ++rr) {
        int ml = rr * 4 + rq;
        int bl = mBase + ml;
        int l = bl & 1023;
        float acc = bias + xz[(size_t)bl * 768 + c] * w3;
        if (l >= 1) acc += xz[(size_t)(bl-1) * 768 + c] * w2;
        if (l >= 2) acc += xz[(size_t)(bl-2) * 768 + c] * w1;
        if (l >= 3) acc += xz[(size_t)(bl-3) * 768 + c] * w0;
        float s = acc / (1.f + __expf(-acc));
        xc[(size_t)bl * DI_ + c] = s;
        T[ml][cl] = s;
    }
    __syncthreads();
    #pragma unroll
    for (int rr = 0; rr < 16; ++rr) {
        int dl = rr * 4 + rq;
        xct[(size_t)(cBase + dl) * 8192 + mBase + cl] = T[cl][dl];
    }
}

// ---------------- selective scan: LDS-combine chunked scan ----------------
// Thread t owns timesteps 4t..4t+3 (256 chunks). All global accesses coalesced
// float4. Combine via LDS: 256-thread segment scans (16 chunks each), 16-thread
// segment-total scan, in-place h_in write-back. No cross-lane shuffles.
__global__ __launch_bounds__(256) void scan_k(
    const float* __restrict__ dtt, const float* __restrict__ dblt,
    const float* __restrict__ xct, const float* __restrict__ zst,
    const float* __restrict__ A_log, const float* __restrict__ Dp,
    float* __restrict__ yft)
{
    const int bd = blockIdx.x;
    const int b = bd / DI_, d = bd % DI_;
    const int tid = threadIdx.x;
    const size_t tb = (size_t)d * 8192 + (size_t)b * 1024;
    const size_t nb = (size_t)b * 1024;
    const int t4 = tid * 4;

    __shared__ float LA[16][257];
    __shared__ float LH[16][257];
    __shared__ float SA[16][17];
    __shared__ float SH[16][17];
    __shared__ float SP[16][17];

    const float4 dt4 = *(const float4*)(dtt + tb + t4);
    const float4 xc4 = *(const float4*)(xct + tb + t4);
    const float dtxc[4] = {dt4.x*xc4.x, dt4.y*xc4.y, dt4.z*xc4.z, dt4.w*xc4.w};

    float And[16];
    #pragma unroll
    for (int n = 0; n < 16; ++n) And[n] = -__expf(A_log[d*16 + n]);

    // pass 1: per-n local 4-step scan (h_in = 0), dump (a-prod, h-local) to LDS
    #pragma unroll
    for (int n = 0; n < 16; ++n) {
        const float4 bs4 = *(const float4*)(dblt + (size_t)(12 + n) * 8192 + nb + t4);
        float a = __expf(dt4.x * And[n]);
        float h = dtxc[0] * bs4.x;
        float apn = a;
        a = __expf(dt4.y * And[n]); h = a*h + dtxc[1]*bs4.y; apn *= a;
        a = __expf(dt4.z * And[n]); h = a*h + dtxc[2]*bs4.z; apn *= a;
        a = __expf(dt4.w * And[n]); h = a*h + dtxc[3]*bs4.w; apn *= a;
        LA[n][tid] = apn; LH[n][tid] = h;
    }
    __syncthreads();

    // level A: 256 threads = (n, segment s); serial scan of 16 chunks
    {
        const int n = tid & 15, s = tid >> 4;
        float A = 1.f, H = 0.f;
        #pragma unroll
        for (int k = 0; k < 16; ++k) {
            const int c = s * 16 + k;
            float a = LA[n][c], h = LH[n][c];
            H = a * H + h;
            A *= a;
        }
        SA[n][s] = A; SH[n][s] = H;
    }
    __syncthreads();

    // level B: 16 threads scan segment totals -> exclusive segment prefixes
    if (tid < 16) {
        float Hp = 0.f;
        #pragma unroll
        for (int s = 0; s < 16; ++s) {
            SP[tid][s] = Hp;
            Hp = SA[tid][s] * Hp + SH[tid][s];
        }
    }
    __syncthreads();

    // level A2: write per-chunk exclusive h_in back into LH (in place)
    {
        const int n = tid & 15, s = tid >> 4;
        float st = SP[n][s];
        #pragma unroll
        for (int k = 0; k < 16; ++k) {
            const int c = s * 16 + k;
            float a = LA[n][c], h = LH[n][c];
            LH[n][c] = st;
            st = a * st + h;
        }
    }
    __syncthreads();

    // pass 2: recompute with h_in, fuse y-reduce + Dp + z-gate
    float y0 = 0.f, y1 = 0.f, y2 = 0.f, y3 = 0.f;
    #pragma unroll
    for (int n = 0; n < 16; ++n) {
        float h = LH[n][tid];
        const float4 bs4 = *(const float4*)(dblt + (size_t)(12 + n) * 8192 + nb + t4);
        const float4 cs4 = *(const float4*)(dblt + (size_t)(28 + n) * 8192 + nb + t4);
        float a;
        a = __expf(dt4.x * And[n]); h = a*h + dtxc[0]*bs4.x; y0 += h * cs4.x;
        a = __expf(dt4.y * And[n]); h = a*h + dtxc[1]*bs4.y; y1 += h * cs4.y;
        a = __expf(dt4.z * And[n]); h = a*h + dtxc[2]*bs4.z; y2 += h * cs4.z;
        a = __expf(dt4.w * And[n]); h = a*h + dtxc[3]*bs4.w; y3 += h * cs4.w;
    }
    const float dp = Dp[d];
    const float4 zs4 = *(const float4*)(zst + tb + t4);
    float4 o;
    o.x = (y0 + xc4.x * dp) * zs4.x;
    o.y = (y1 + xc4.y * dp) * zs4.y;
    o.z = (y2 + xc4.z * dp) * zs4.z;
    o.w = (y3 + xc4.w * dp) * zs4.w;
    *(float4*)(yft + tb + t4) = o;
}

extern "C" void kernel_launch(void* const* d_in, const int* in_sizes, int n_in,
                              void* d_out, int out_size, void* d_ws, size_t ws_size,
                              hipStream_t stream) {
    const float* x     = (const float*)d_in[0];
    const float* w1    = (const float*)d_in[1];
    const float* g1    = (const float*)d_in[2];
    const float* b1    = (const float*)d_in[3];
    const float* m1    = (const float*)d_in[4];
    const float* v1    = (const float*)d_in[5];
    const float* w2    = (const float*)d_in[6];
    const float* g2    = (const float*)d_in[7];
    const float* b2    = (const float*)d_in[8];
    const float* m2    = (const float*)d_in[9];
    const float* v2    = (const float*)d_in[10];
    const float* in_w  = (const float*)d_in[11];
    const float* cw    = (const float*)d_in[12];
    const float* cb    = (const float*)d_in[13];
    const float* xp_w  = (const float*)d_in[14];
    const float* dt_w  = (const float*)d_in[15];
    const float* dt_b  = (const float*)d_in[16];
    const float* A_log = (const float*)d_in[17];
    const float* Dp    = (const float*)d_in[18];
    const float* out_w = (const float*)d_in[19];
    const float* w3    = (const float*)d_in[20];
    const float* g3    = (const float*)d_in[21];
    const float* b3    = (const float*)d_in[22];
    const float* m3    = (const float*)d_in[23];
    const float* v3    = (const float*)d_in[24];
    const float* w4    = (const float*)d_in[25];
    const float* g4    = (const float*)d_in[26];
    const float* b4    = (const float*)d_in[27];
    const float* m4    = (const float*)d_in[28];
    const float* v4    = (const float*)d_in[29];

    float* ws   = (float*)d_ws;
    float* t1   = ws + O_T1;
    float* xzb  = ws + O_XZ;
    float* xcb  = ws + O_XC;
    float* dblt = ws + O_DBLT;
    float* xct  = ws + O_XCT;
    float* zst  = ws + O_ZST;
    float* dtt  = ws + O_DTT;
    float* yft  = ws + O_YFT;
    float* ub   = ws + O_U;
    // bf16 t2 + bf16 in_w live in the freed f32-t2 region (6.29 MB)
    u16* t2b  = (u16*)(ws + O_T2);
    u16* inwb = t2b + (size_t)8192 * 192;
    // bf16 arena
    u16* Xb4 = (u16*)(ws + O_V);
    u16* Xb1 = Xb4 + (size_t)8192 * 192;
    u16* wt1 = Xb1 + (size_t)8192 * 96;
    u16* wt4 = wt1 + (size_t)9 * 96 * 96;

    // 0) converters
    cvt_w_k<<<64, 256, 0, stream>>>(w1, wt1, 96, 96);
    cvt_w_k<<<192, 256, 0, stream>>>(w4, wt4, 192, 192);
    cvt_x_k<<<3072, 256, 0, stream>>>(x, Xb1);
    cvt_e_k<<<144, 256, 0, stream>>>(in_w, inwb, 768 * 192);

    // 1) conv3x3 96->96 + BN + GELU (bf16 MFMA) -> t1 f32 NHWC
    conv3x3_mfma_k<96, 96, 32, 0><<<dim3(128, 3), 256, 0, stream>>>(
        Xb1, wt1, g1, b1, m1, v1, t1);

    // 2) 1x1 conv 96->192 + BN + SiLU -> t2 bf16 (8192,192)
    gemm_k<EPI_BN_SILU, 2, 0><<<dim3(128, 3), 256, 0, stream>>>(
        8192, 192, 96, 96, t1, w2, t2b, g2, b2, m2, v2);

    // 3) in-proj (bf16 MFMA): xz = t2 @ in_w^T  (8192,768) f32
    gemm_mfma_k<64><<<dim3(128, 12), 256, 0, stream>>>(
        8192, 768, 192, t2b, inwb, xzb);

    // 4a) z-gate: zs_t = silu(z)^T
    ztr_k<<<dim3(128, 6), 256, 0, stream>>>(xzb, zst);

    // 4b) depthwise causal conv + SiLU -> xc row-major + xc_t
    dwconv_k<<<dim3(128, 6), 256, 0, stream>>>(xzb, cw, cb, xcb, xct);

    // 5) x-proj: dbl_t = (xc @ xp_w^T)^T  [44][8192]
    gemm_k<EPI_NONE, 3, 0><<<dim3(128, 1), 256, 0, stream>>>(
        8192, 44, 384, 384, xcb, xp_w, dblt, nullptr, nullptr, nullptr, nullptr);

    // 6) dt_t = softplus(dbl[:, :12] @ dt_w^T + dt_b)^T  [384][8192]
    gemm_k<EPI_SP, 3, 1><<<dim3(128, 6), 256, 0, stream>>>(
        8192, 384, 12, 8192, dblt, dt_w, dtt, dt_b, nullptr, nullptr, nullptr);

    // 7) selective scan + gate -> yf_t [384][8192]
    scan_k<<<8 * DI_, 256, 0, stream>>>(dtt, dblt, xct, zst, A_log, Dp, yft);

    // 8) out-proj: u = yf @ out_w^T (A transposed)
    gemm_k<EPI_NONE, 0, 1><<<dim3(128, 3), 256, 0, stream>>>(
        8192, 192, 384, 8192, yft, out_w, ub, nullptr, nullptr, nullptr, nullptr);

    // 9) 1x1 conv 192->192 + BN + SiLU -> Xb4 bf16 NHWC
    gemm_k<EPI_BN_SILU, 2, 0><<<dim3(128, 3), 256, 0, stream>>>(
        8192, 192, 192, 192, ub, w3, Xb4, g3, b3, m3, v3);

    // 10) conv3x3 192->192 + BN + GELU (bf16 MFMA) -> out f32 NCHW
    conv3x3_mfma_k<192, 192, 64, 1><<<dim3(128, 3), 256, 0, stream>>>(
        Xb4, wt4, g4, b4, m4, v4, (float*)d_out);
}

// Round 8
// 300.764 us; speedup vs baseline: 2.4238x; 1.0847x over previous
//
#include <hip/hip_runtime.h>
#include <hip/hip_bf16.h>

using u16 = unsigned short;
using short8 = __attribute__((ext_vector_type(8))) short;
using f32x4  = __attribute__((ext_vector_type(4))) float;

constexpr int D_   = 192;
constexpr int DI_  = 384;

// ---- workspace layout ----
// f32 regions (offsets in floats)
constexpr size_t O_XZ   = 0;                        // 8192*768 xz; later dt_t+yf_t
constexpr size_t O_XCT  = O_XZ + (size_t)8192*768;  // 384*8192 xc transposed f32
constexpr size_t O_ZST  = O_XCT + (size_t)384*8192; // 384*8192 silu(z) transposed f32
constexpr size_t O_DBLT = O_ZST + (size_t)384*8192; // 32*8192  Bs/Cs transposed f32
constexpr size_t O_B16  = O_DBLT + (size_t)32*8192; // bf16 arena start
constexpr size_t O_DTT  = O_XZ;                     // overlays dead xz
constexpr size_t O_YFT  = O_XZ + (size_t)384*8192;  // overlays dead xz
// bf16 arena offsets (in u16, from O_B16)
constexpr size_t B_T1   = 0;                        // 8192*96   t1 bf16 NHWC
constexpr size_t B_T2   = B_T1 + (size_t)8192*96;   // 8192*192  t2 bf16
constexpr size_t B_XC   = B_T2 + (size_t)8192*192;  // 8192*384  xc bf16 row-major
constexpr size_t B_YF   = B_XC + (size_t)8192*384;  // 8192*384  yf bf16 row-major
constexpr size_t B_XB1  = B_YF + (size_t)8192*384;  // 8192*96   input bf16 NHWC
constexpr size_t B_XB4  = B_XB1 + (size_t)8192*96;  // 8192*192  conv4 input bf16 NHWC
constexpr size_t B_WT1  = B_XB4 + (size_t)8192*192; // 9*96*96
constexpr size_t B_WT4  = B_WT1 + (size_t)9*96*96;  // 9*192*192
constexpr size_t B_INW  = B_WT4 + (size_t)9*192*192;// 768*192
constexpr size_t B_W2   = B_INW + (size_t)768*192;  // 192*96
constexpr size_t B_XP   = B_W2  + (size_t)192*96;   // 32*384
constexpr size_t B_WDT  = B_XP  + (size_t)32*384;   // 384*384
constexpr size_t B_WOW  = B_WDT + (size_t)384*384;  // 192*384

__device__ __forceinline__ u16 f2b(float f) {
    __hip_bfloat16 h = __float2bfloat16(f);
    return *reinterpret_cast<u16*>(&h);
}

// ---------------- fused weight prep: 7 jobs in one dispatch ----------------
struct PrepArgs {
    const float *w1, *w4, *in_w, *w2, *xp_w, *dt_w, *w3, *out_w;
    u16 *wt1, *wt4, *inwb, *w2b, *xpb, *Wdt, *Wow;
};

__global__ __launch_bounds__(256) void prep_k(PrepArgs a) {
    const int job = blockIdx.y;
    const int stride = gridDim.x * 256;
    const int i0 = blockIdx.x * 256 + threadIdx.x;
    switch (job) {
    case 0: // w1 [96][96][3][3] -> [9][96][96]
        for (int i = i0; i < 9*96*96; i += stride) {
            int ci = i % 96, co = (i / 96) % 96, t = i / (96*96);
            a.wt1[i] = f2b(a.w1[((size_t)co*96 + ci)*9 + t]);
        } break;
    case 1: // w4 [192][192][3][3] -> [9][192][192]
        for (int i = i0; i < 9*192*192; i += stride) {
            int ci = i % 192, co = (i / 192) % 192, t = i / (192*192);
            a.wt4[i] = f2b(a.w4[((size_t)co*192 + ci)*9 + t]);
        } break;
    case 2: // in_w [768][192] convert
        for (int i = i0; i < 768*192; i += stride) a.inwb[i] = f2b(a.in_w[i]);
        break;
    case 3: // w2 [192][96] convert
        for (int i = i0; i < 192*96; i += stride) a.w2b[i] = f2b(a.w2[i]);
        break;
    case 4: // xp_w rows 12..43 -> [32][384]
        for (int i = i0; i < 32*384; i += stride) {
            int r = i / 384, c = i % 384;
            a.xpb[i] = f2b(a.xp_w[(size_t)(12 + r)*384 + c]);
        } break;
    case 5: // Wdt[r][c] = sum_k dt_w[r][k] * xp_w[k][c]  (384x384, K=12)
        for (int i = i0; i < 384*384; i += stride) {
            int r = i / 384, c = i % 384;
            float s = 0.f;
            #pragma unroll
            for (int k = 0; k < 12; ++k) s += a.dt_w[r*12 + k] * a.xp_w[(size_t)k*384 + c];
            a.Wdt[i] = f2b(s);
        } break;
    case 6: // Wow[o][d] = sum_j w3[o][j] * out_w[j][d]  (192x384, K=192)
        for (int i = i0; i < 192*384; i += stride) {
            int o = i / 384, d = i % 384;
            float s = 0.f;
            for (int j = 0; j < 192; ++j) s += a.w3[(size_t)o*192 + j] * a.out_w[(size_t)j*384 + d];
            a.Wow[i] = f2b(s);
        } break;
    }
}

// ---------------- x: NCHW f32 -> NHWC bf16 ----------------
__global__ __launch_bounds__(256) void cvt_x_k(
    const float* __restrict__ src, u16* __restrict__ dst)
{
    int idx = blockIdx.x * 256 + threadIdx.x;   // 8192*96
    int ci = idx % 96;
    int px = idx / 96;
    dst[idx] = f2b(src[(((size_t)(px >> 10) * 96 + ci) << 10) | (size_t)(px & 1023)]);
}

// ---------------- 3x3 conv as bf16-MFMA shift-GEMM + BN + exact GELU ----------------
// OUTM 0: f32 NHWC; 1: f32 NCHW; 2: bf16 NHWC
template<int CIN, int COUT, int NTILE, int OUTM>
__global__ __launch_bounds__(256) void conv3x3_mfma_k(
    const u16* __restrict__ Xb, const u16* __restrict__ Wt,
    const float* __restrict__ g, const float* __restrict__ b,
    const float* __restrict__ m, const float* __restrict__ v,
    void* __restrict__ out)
{
    constexpr int LDA = 40;
    constexpr int NT = NTILE / 16;
    __shared__ u16 As[64 * LDA];
    __shared__ u16 Bs[NTILE * LDA];
    const int tid = threadIdx.x;
    const int wave = tid >> 6, lane = tid & 63;
    const int quad = lane >> 4, l16 = lane & 15;
    const int rowBase = blockIdx.x * 64;
    const int colBase = blockIdx.y * NTILE;

    f32x4 acc[NT];
    #pragma unroll
    for (int nt = 0; nt < NT; ++nt)
        #pragma unroll
        for (int i = 0; i < 4; ++i) acc[nt][i] = 0.f;

    const int ar = tid >> 2, aseg = tid & 3;
    const int apx = rowBase + ar;
    const int ah = (apx >> 5) & 31, aw = apx & 31;

    for (int t = 0; t < 9; ++t) {
        const int dr = t / 3 - 1, dc = t % 3 - 1;
        const bool avalid = ((unsigned)(ah + dr) < 32u) && ((unsigned)(aw + dc) < 32u);
        const int apxs = apx + dr * 32 + dc;
        for (int ci0 = 0; ci0 < CIN; ci0 += 32) {
            __syncthreads();
            uint4 va = make_uint4(0u, 0u, 0u, 0u);
            if (avalid)
                va = *(const uint4*)(Xb + (size_t)apxs * CIN + ci0 + aseg * 8);
            *(uint4*)(As + ar * LDA + aseg * 8) = va;
            if (tid < NTILE * 4) {
                int r = tid >> 2, seg = tid & 3;
                uint4 vb = *(const uint4*)(Wt + ((size_t)t * COUT + colBase + r) * CIN + ci0 + seg * 8);
                *(uint4*)(Bs + r * LDA + seg * 8) = vb;
            }
            __syncthreads();
            short8 a = *(const short8*)(As + (wave * 16 + l16) * LDA + quad * 8);
            #pragma unroll
            for (int nt = 0; nt < NT; ++nt) {
                short8 bf = *(const short8*)(Bs + (nt * 16 + l16) * LDA + quad * 8);
                acc[nt] = __builtin_amdgcn_mfma_f32_16x16x32_bf16(a, bf, acc[nt], 0, 0, 0);
            }
        }
    }

    const int px0 = rowBase + wave * 16 + quad * 4;
    #pragma unroll
    for (int nt = 0; nt < NT; ++nt) {
        const int co = colBase + nt * 16 + l16;
        const float sc = g[co] * rsqrtf(v[co] + 1e-5f);
        const float bb = b[co] - m[co] * sc;
        float o[4];
        #pragma unroll
        for (int r = 0; r < 4; ++r) {
            float xv = acc[nt][r] * sc + bb;
            o[r] = 0.5f * xv * (1.f + erff(xv * 0.70710678f));
        }
        if (OUTM == 0) {
            #pragma unroll
            for (int r = 0; r < 4; ++r)
                ((float*)out)[(size_t)(px0 + r) * COUT + co] = o[r];
        } else if (OUTM == 2) {
            #pragma unroll
            for (int r = 0; r < 4; ++r)
                ((u16*)out)[(size_t)(px0 + r) * COUT + co] = f2b(o[r]);
        } else {
            const int img = px0 >> 10, off = px0 & 1023;
            *(float4*)((float*)out + (((size_t)img * COUT + co) << 10) + off) =
                make_float4(o[0], o[1], o[2], o[3]);
        }
    }
}

// ---------------- bf16 MFMA GEMM with epilogues ----------------
// C[M,N] = A[M,K] @ B[N,K]^T.  A,B bf16 row-major, K%32==0, M%64==0, N%NTILE==0.
// EPI: 0 none, 1 BN+SiLU (p0..p3 = g,b,m,v), 2 softplus(+p0 bias)
// OUTM: 0 f32 row-major, 2 bf16 row-major, 3 f32 transposed C_t[co*M+row]
template<int NTILE, int EPI, int OUTM>
__global__ __launch_bounds__(256) void gemm_mfma_k(
    int M, int N, int K,
    const u16* __restrict__ Ab, const u16* __restrict__ Bb, void* __restrict__ C,
    const float* __restrict__ p0, const float* __restrict__ p1,
    const float* __restrict__ p2, const float* __restrict__ p3)
{
    constexpr int LDA = 40;
    constexpr int NT = NTILE / 16;
    __shared__ u16 As[64 * LDA];
    __shared__ u16 Bs[NTILE * LDA];
    const int tid = threadIdx.x;
    const int wave = tid >> 6, lane = tid & 63;
    const int quad = lane >> 4, l16 = lane & 15;
    const int rowBase = blockIdx.x * 64;
    const int colBase = blockIdx.y * NTILE;

    f32x4 acc[NT];
    #pragma unroll
    for (int nt = 0; nt < NT; ++nt)
        #pragma unroll
        for (int i = 0; i < 4; ++i) acc[nt][i] = 0.f;

    const int ar = tid >> 2, aseg = tid & 3;

    for (int k0 = 0; k0 < K; k0 += 32) {
        __syncthreads();
        uint4 va = *(const uint4*)(Ab + (size_t)(rowBase + ar) * K + k0 + aseg * 8);
        *(uint4*)(As + ar * LDA + aseg * 8) = va;
        if (tid < NTILE * 4) {
            int r = tid >> 2, seg = tid & 3;
            uint4 vb = *(const uint4*)(Bb + (size_t)(colBase + r) * K + k0 + seg * 8);
            *(uint4*)(Bs + r * LDA + seg * 8) = vb;
        }
        __syncthreads();
        short8 a = *(const short8*)(As + (wave * 16 + l16) * LDA + quad * 8);
        #pragma unroll
        for (int nt = 0; nt < NT; ++nt) {
            short8 bf = *(const short8*)(Bs + (nt * 16 + l16) * LDA + quad * 8);
            acc[nt] = __builtin_amdgcn_mfma_f32_16x16x32_bf16(a, bf, acc[nt], 0, 0, 0);
        }
    }

    const int px0 = rowBase + wave * 16 + quad * 4;
    #pragma unroll
    for (int nt = 0; nt < NT; ++nt) {
        const int co = colBase + nt * 16 + l16;
        float sc = 0.f, bb = 0.f;
        if (EPI == 1) {
            sc = p0[co] * rsqrtf(p3[co] + 1e-5f);
            bb = p1[co] - p2[co] * sc;
        } else if (EPI == 2) {
            bb = p0[co];
        }
        float o[4];
        #pragma unroll
        for (int r = 0; r < 4; ++r) {
            float xv = acc[nt][r];
            if (EPI == 1) {
                xv = xv * sc + bb;
                xv = xv / (1.f + __expf(-xv));
            } else if (EPI == 2) {
                xv += bb;
                xv = (xv > 20.f) ? xv : log1pf(__expf(xv));
            }
            o[r] = xv;
        }
        if (OUTM == 3) {
            *(float4*)((float*)C + (size_t)co * M + px0) =
                make_float4(o[0], o[1], o[2], o[3]);
        } else if (OUTM == 2) {
            #pragma unroll
            for (int r = 0; r < 4; ++r)
                ((u16*)C)[(size_t)(px0 + r) * N + co] = f2b(o[r]);
        } else {
            #pragma unroll
            for (int r = 0; r < 4; ++r)
                ((float*)C)[(size_t)(px0 + r) * N + co] = o[r];
        }
    }
}

// ---------------- z-gate extract: zs_t[d][m] = silu(xz[m][384+d]) ----------------
__global__ __launch_bounds__(256) void ztr_k(
    const float* __restrict__ xz, float* __restrict__ zst)
{
    __shared__ float T[64][65];
    const int tid = threadIdx.x;
    const int cl = tid & 63, rq = tid >> 6;
    const int mBase = blockIdx.x * 64, dBase = blockIdx.y * 64;
    #pragma unroll
    for (int rr = 0; rr < 16; ++rr) {
        int ml = rr * 4 + rq;
        float zv = xz[(size_t)(mBase + ml) * 768 + 384 + dBase + cl];
        T[ml][cl] = zv / (1.f + __expf(-zv));
    }
    __syncthreads();
    #pragma unroll
    for (int rr = 0; rr < 16; ++rr) {
        int dl = rr * 4 + rq;
        zst[(size_t)(dBase + dl) * 8192 + mBase + cl] = T[cl][dl];
    }
}

// ---------------- yf transpose: [384][8192] f32 -> [8192][384] bf16 ----------------
__global__ __launch_bounds__(256) void tr_k(
    const float* __restrict__ yft, u16* __restrict__ yfb)
{
    __shared__ float T[64][65];
    const int tid = threadIdx.x;
    const int cl = tid & 63, rq = tid >> 6;
    const int mBase = blockIdx.x * 64, dBase = blockIdx.y * 64;
    #pragma unroll
    for (int rr = 0; rr < 16; ++rr) {
        int dl = rr * 4 + rq;
        T[dl][cl] = yft[(size_t)(dBase + dl) * 8192 + mBase + cl];
    }
    __syncthreads();
    #pragma unroll
    for (int rr = 0; rr < 16; ++rr) {
        int ml = rr * 4 + rq;
        yfb[(size_t)(mBase + ml) * 384 + dBase + cl] = f2b(T[cl][ml]);
    }
}

// ---------------- depthwise causal conv (K=4) + SiLU, bf16 row-major + f32 transposed ----------------
__global__ __launch_bounds__(256) void dwconv_k(
    const float* __restrict__ xz, const float* __restrict__ cw, const float* __restrict__ cb,
    u16* __restrict__ xcb, float* __restrict__ xct)
{
    __shared__ float T[64][65];
    const int tid = threadIdx.x;
    const int cl = tid & 63, rq = tid >> 6;
    const int mBase = blockIdx.x * 64, cBase = blockIdx.y * 64;
    const int c = cBase + cl;
    const float w0 = cw[c*4+0], w1 = cw[c*4+1], w2 = cw[c*4+2], w3 = cw[c*4+3];
    const float bias = cb[c];
    #pragma unroll
    for (int rr = 0; rr < 16; ++rr) {
        int ml = rr * 4 + rq;
        int bl = mBase + ml;
        int l = bl & 1023;
        float acc = bias + xz[(size_t)bl * 768 + c] * w3;
        if (l >= 1) acc += xz[(size_t)(bl-1) * 768 + c] * w2;
        if (l >= 2) acc += xz[(size_t)(bl-2) * 768 + c] * w1;
        if (l >= 3) acc += xz[(size_t)(bl-3) * 768 + c] * w0;
        float s = acc / (1.f + __expf(-acc));
        xcb[(size_t)bl * DI_ + c] = f2b(s);
        T[ml][cl] = s;
    }
    __syncthreads();
    #pragma unroll
    for (int rr = 0; rr < 16; ++rr) {
        int dl = rr * 4 + rq;
        xct[(size_t)(cBase + dl) * 8192 + mBase + cl] = T[cl][dl];
    }
}

// ---------------- selective scan: LDS-combine chunked scan ----------------
// dblt rows: 0..15 = Bs[n], 16..31 = Cs[n]
__global__ __launch_bounds__(256) void scan_k(
    const float* __restrict__ dtt, const float* __restrict__ dblt,
    const float* __restrict__ xct, const float* __restrict__ zst,
    const float* __restrict__ A_log, const float* __restrict__ Dp,
    float* __restrict__ yft)
{
    const int bd = blockIdx.x;
    const int b = bd / DI_, d = bd % DI_;
    const int tid = threadIdx.x;
    const size_t tb = (size_t)d * 8192 + (size_t)b * 1024;
    const size_t nb = (size_t)b * 1024;
    const int t4 = tid * 4;

    __shared__ float LA[16][257];
    __shared__ float LH[16][257];
    __shared__ float SA[16][17];
    __shared__ float SH[16][17];
    __shared__ float SP[16][17];

    const float4 dt4 = *(const float4*)(dtt + tb + t4);
    const float4 xc4 = *(const float4*)(xct + tb + t4);
    const float dtxc[4] = {dt4.x*xc4.x, dt4.y*xc4.y, dt4.z*xc4.z, dt4.w*xc4.w};

    float And[16];
    #pragma unroll
    for (int n = 0; n < 16; ++n) And[n] = -__expf(A_log[d*16 + n]);

    #pragma unroll
    for (int n = 0; n < 16; ++n) {
        const float4 bs4 = *(const float4*)(dblt + (size_t)n * 8192 + nb + t4);
        float a = __expf(dt4.x * And[n]);
        float h = dtxc[0] * bs4.x;
        float apn = a;
        a = __expf(dt4.y * And[n]); h = a*h + dtxc[1]*bs4.y; apn *= a;
        a = __expf(dt4.z * And[n]); h = a*h + dtxc[2]*bs4.z; apn *= a;
        a = __expf(dt4.w * And[n]); h = a*h + dtxc[3]*bs4.w; apn *= a;
        LA[n][tid] = apn; LH[n][tid] = h;
    }
    __syncthreads();

    {
        const int n = tid & 15, s = tid >> 4;
        float A = 1.f, H = 0.f;
        #pragma unroll
        for (int k = 0; k < 16; ++k) {
            const int c = s * 16 + k;
            float a = LA[n][c], h = LH[n][c];
            H = a * H + h;
            A *= a;
        }
        SA[n][s] = A; SH[n][s] = H;
    }
    __syncthreads();

    if (tid < 16) {
        float Hp = 0.f;
        #pragma unroll
        for (int s = 0; s < 16; ++s) {
            SP[tid][s] = Hp;
            Hp = SA[tid][s] * Hp + SH[tid][s];
        }
    }
    __syncthreads();

    {
        const int n = tid & 15, s = tid >> 4;
        float st = SP[n][s];
        #pragma unroll
        for (int k = 0; k < 16; ++k) {
            const int c = s * 16 + k;
            float a = LA[n][c], h = LH[n][c];
            LH[n][c] = st;
            st = a * st + h;
        }
    }
    __syncthreads();

    float y0 = 0.f, y1 = 0.f, y2 = 0.f, y3 = 0.f;
    #pragma unroll
    for (int n = 0; n < 16; ++n) {
        float h = LH[n][tid];
        const float4 bs4 = *(const float4*)(dblt + (size_t)n * 8192 + nb + t4);
        const float4 cs4 = *(const float4*)(dblt + (size_t)(16 + n) * 8192 + nb + t4);
        float a;
        a = __expf(dt4.x * And[n]); h = a*h + dtxc[0]*bs4.x; y0 += h * cs4.x;
        a = __expf(dt4.y * And[n]); h = a*h + dtxc[1]*bs4.y; y1 += h * cs4.y;
        a = __expf(dt4.z * And[n]); h = a*h + dtxc[2]*bs4.z; y2 += h * cs4.z;
        a = __expf(dt4.w * And[n]); h = a*h + dtxc[3]*bs4.w; y3 += h * cs4.w;
    }
    const float dp = Dp[d];
    const float4 zs4 = *(const float4*)(zst + tb + t4);
    float4 o;
    o.x = (y0 + xc4.x * dp) * zs4.x;
    o.y = (y1 + xc4.y * dp) * zs4.y;
    o.z = (y2 + xc4.z * dp) * zs4.z;
    o.w = (y3 + xc4.w * dp) * zs4.w;
    *(float4*)(yft + tb + t4) = o;
}

extern "C" void kernel_launch(void* const* d_in, const int* in_sizes, int n_in,
                              void* d_out, int out_size, void* d_ws, size_t ws_size,
                              hipStream_t stream) {
    const float* x     = (const float*)d_in[0];
    const float* w1    = (const float*)d_in[1];
    const float* g1    = (const float*)d_in[2];
    const float* b1    = (const float*)d_in[3];
    const float* m1    = (const float*)d_in[4];
    const float* v1    = (const float*)d_in[5];
    const float* w2    = (const float*)d_in[6];
    const float* g2    = (const float*)d_in[7];
    const float* b2    = (const float*)d_in[8];
    const float* m2    = (const float*)d_in[9];
    const float* v2    = (const float*)d_in[10];
    const float* in_w  = (const float*)d_in[11];
    const float* cw    = (const float*)d_in[12];
    const float* cb    = (const float*)d_in[13];
    const float* xp_w  = (const float*)d_in[14];
    const float* dt_w  = (const float*)d_in[15];
    const float* dt_b  = (const float*)d_in[16];
    const float* A_log = (const float*)d_in[17];
    const float* Dp    = (const float*)d_in[18];
    const float* out_w = (const float*)d_in[19];
    const float* w3    = (const float*)d_in[20];
    const float* g3    = (const float*)d_in[21];
    const float* b3    = (const float*)d_in[22];
    const float* m3    = (const float*)d_in[23];
    const float* v3    = (const float*)d_in[24];
    const float* w4    = (const float*)d_in[25];
    const float* g4    = (const float*)d_in[26];
    const float* b4    = (const float*)d_in[27];
    const float* m4    = (const float*)d_in[28];
    const float* v4    = (const float*)d_in[29];

    float* ws   = (float*)d_ws;
    float* xzb  = ws + O_XZ;
    float* xct  = ws + O_XCT;
    float* zst  = ws + O_ZST;
    float* dblt = ws + O_DBLT;
    float* dtt  = ws + O_DTT;
    float* yft  = ws + O_YFT;
    u16* b16  = (u16*)(ws + O_B16);
    u16* t1b  = b16 + B_T1;
    u16* t2b  = b16 + B_T2;
    u16* xcb  = b16 + B_XC;
    u16* yfb  = b16 + B_YF;
    u16* Xb1  = b16 + B_XB1;
    u16* Xb4  = b16 + B_XB4;
    u16* wt1  = b16 + B_WT1;
    u16* wt4  = b16 + B_WT4;
    u16* inwb = b16 + B_INW;
    u16* w2b  = b16 + B_W2;
    u16* xpb  = b16 + B_XP;
    u16* Wdt  = b16 + B_WDT;
    u16* Wow  = b16 + B_WOW;

    // 0) weight prep (7 jobs) + input convert
    PrepArgs pa;
    pa.w1 = w1; pa.w4 = w4; pa.in_w = in_w; pa.w2 = w2; pa.xp_w = xp_w;
    pa.dt_w = dt_w; pa.w3 = w3; pa.out_w = out_w;
    pa.wt1 = wt1; pa.wt4 = wt4; pa.inwb = inwb; pa.w2b = w2b; pa.xpb = xpb;
    pa.Wdt = Wdt; pa.Wow = Wow;
    prep_k<<<dim3(256, 7), 256, 0, stream>>>(pa);
    cvt_x_k<<<3072, 256, 0, stream>>>(x, Xb1);

    // 1) conv3x3 96->96 + BN + GELU (MFMA) -> t1 bf16 NHWC
    conv3x3_mfma_k<96, 96, 32, 2><<<dim3(128, 3), 256, 0, stream>>>(
        Xb1, wt1, g1, b1, m1, v1, t1b);

    // 2) 1x1 conv 96->192 + BN + SiLU (MFMA) -> t2 bf16
    gemm_mfma_k<64, 1, 2><<<dim3(128, 3), 256, 0, stream>>>(
        8192, 192, 96, t1b, w2b, t2b, g2, b2, m2, v2);

    // 3) in-proj (MFMA): xz = t2 @ in_w^T  (8192,768) f32
    gemm_mfma_k<64, 0, 0><<<dim3(128, 12), 256, 0, stream>>>(
        8192, 768, 192, t2b, inwb, xzb, nullptr, nullptr, nullptr, nullptr);

    // 4a) z-gate: zs_t = silu(z)^T
    ztr_k<<<dim3(128, 6), 256, 0, stream>>>(xzb, zst);

    // 4b) depthwise causal conv + SiLU -> xc bf16 row-major + xc_t f32
    dwconv_k<<<dim3(128, 6), 256, 0, stream>>>(xzb, cw, cb, xcb, xct);

    // 5) x-proj Bs/Cs (MFMA): dbl_t = (xc @ xp_w[12:44]^T)^T  [32][8192] f32
    gemm_mfma_k<32, 0, 3><<<dim3(128, 1), 256, 0, stream>>>(
        8192, 32, 384, xcb, xpb, dblt, nullptr, nullptr, nullptr, nullptr);

    // 6) dt (MFMA, fused weight): dt_t = softplus(xc @ Wdt^T + dt_b)^T [384][8192]
    gemm_mfma_k<64, 2, 3><<<dim3(128, 6), 256, 0, stream>>>(
        8192, 384, 384, xcb, Wdt, dtt, dt_b, nullptr, nullptr, nullptr);

    // 7) selective scan + gate -> yf_t [384][8192] f32
    scan_k<<<8 * DI_, 256, 0, stream>>>(dtt, dblt, xct, zst, A_log, Dp, yft);

    // 8) yf transpose -> bf16 row-major
    tr_k<<<dim3(128, 6), 256, 0, stream>>>(yft, yfb);

    // 9) fused out-proj + 1x1 conv3 + BN + SiLU (MFMA): Xb4 = silu(bn(yf @ Wow^T))
    gemm_mfma_k<64, 1, 2><<<dim3(128, 3), 256, 0, stream>>>(
        8192, 192, 384, yfb, Wow, Xb4, g3, b3, m3, v3);

    // 10) conv3x3 192->192 + BN + GELU (MFMA) -> out f32 NCHW
    conv3x3_mfma_k<192, 192, 64, 1><<<dim3(128, 3), 256, 0, stream>>>(
        Xb4, wt4, g4, b4, m4, v4, (float*)d_out);
}

// Round 9
// 277.208 us; speedup vs baseline: 2.6297x; 1.0850x over previous
//
#include <hip/hip_runtime.h>
#include <hip/hip_bf16.h>

using u16 = unsigned short;
using short8 = __attribute__((ext_vector_type(8))) short;
using f32x4  = __attribute__((ext_vector_type(4))) float;

constexpr int DI_ = 384;

// ---- workspace layout ----
constexpr size_t O_XZ   = 0;                         // 8192*384 x-half of in-proj; later dtt
constexpr size_t O_XCT  = O_XZ  + (size_t)8192*384;  // 384*8192 xc transposed f32
constexpr size_t O_ZST  = O_XCT + (size_t)384*8192;  // 384*8192 silu(z) transposed f32
constexpr size_t O_DBLT = O_ZST + (size_t)384*8192;  // 32*8192  Bs/Cs transposed f32
constexpr size_t O_YFT  = O_DBLT+ (size_t)32*8192;   // 384*8192 scan output f32
constexpr size_t O_B16  = O_YFT + (size_t)384*8192;  // bf16 arena start
constexpr size_t O_DTT  = O_XZ;                      // overlays dead xz
// bf16 arena offsets (u16)
constexpr size_t B_T1  = 0;                          // 8192*96
constexpr size_t B_T2  = B_T1  + (size_t)8192*96;    // 8192*192
constexpr size_t B_XC  = B_T2  + (size_t)8192*192;   // 8192*384
constexpr size_t B_XB1 = B_XC  + (size_t)8192*384;   // 8192*96
constexpr size_t B_XB4 = B_XB1 + (size_t)8192*96;    // 8192*192
constexpr size_t B_WT1 = B_XB4 + (size_t)8192*192;   // 9*96*96
constexpr size_t B_WT4 = B_WT1 + (size_t)9*96*96;    // 9*192*192
constexpr size_t B_INW = B_WT4 + (size_t)9*192*192;  // 768*192
constexpr size_t B_W2  = B_INW + (size_t)768*192;    // 192*96
constexpr size_t B_XP  = B_W2  + (size_t)192*96;     // 32*384
constexpr size_t B_WDT = B_XP  + (size_t)32*384;     // 384*384
constexpr size_t B_WOW = B_WDT + (size_t)384*384;    // 192*384

__device__ __forceinline__ u16 f2b(float f) {
    __hip_bfloat16 h = __float2bfloat16(f);
    return *reinterpret_cast<u16*>(&h);
}

// ---------------- fused weight prep + input convert: 8 jobs ----------------
struct PrepArgs {
    const float *w1, *w4, *in_w, *w2, *xp_w, *dt_w, *w3, *out_w, *x;
    u16 *wt1, *wt4, *inwb, *w2b, *xpb, *Wdt, *Wow, *Xb1;
};

__global__ __launch_bounds__(256) void prep_k(PrepArgs a) {
    const int job = blockIdx.y;
    const int stride = gridDim.x * 256;
    const int i0 = blockIdx.x * 256 + threadIdx.x;
    switch (job) {
    case 0:
        for (int i = i0; i < 9*96*96; i += stride) {
            int ci = i % 96, co = (i / 96) % 96, t = i / (96*96);
            a.wt1[i] = f2b(a.w1[((size_t)co*96 + ci)*9 + t]);
        } break;
    case 1:
        for (int i = i0; i < 9*192*192; i += stride) {
            int ci = i % 192, co = (i / 192) % 192, t = i / (192*192);
            a.wt4[i] = f2b(a.w4[((size_t)co*192 + ci)*9 + t]);
        } break;
    case 2:
        for (int i = i0; i < 768*192; i += stride) a.inwb[i] = f2b(a.in_w[i]);
        break;
    case 3:
        for (int i = i0; i < 192*96; i += stride) a.w2b[i] = f2b(a.w2[i]);
        break;
    case 4: // xp_w rows 12..43 -> [32][384]
        for (int i = i0; i < 32*384; i += stride) {
            int r = i / 384, c = i % 384;
            a.xpb[i] = f2b(a.xp_w[(size_t)(12 + r)*384 + c]);
        } break;
    case 5: // Wdt = dt_w @ xp_w[:12]
        for (int i = i0; i < 384*384; i += stride) {
            int r = i / 384, c = i % 384;
            float s = 0.f;
            #pragma unroll
            for (int k = 0; k < 12; ++k) s += a.dt_w[r*12 + k] * a.xp_w[(size_t)k*384 + c];
            a.Wdt[i] = f2b(s);
        } break;
    case 6: // Wow = w3 @ out_w
        for (int i = i0; i < 192*384; i += stride) {
            int o = i / 384, d = i % 384;
            float s = 0.f;
            for (int j = 0; j < 192; ++j) s += a.w3[(size_t)o*192 + j] * a.out_w[(size_t)j*384 + d];
            a.Wow[i] = f2b(s);
        } break;
    case 7: // x NCHW f32 -> NHWC bf16
        for (int i = i0; i < 8192*96; i += stride) {
            int ci = i % 96, px = i / 96;
            a.Xb1[i] = f2b(a.x[(((size_t)(px >> 10) * 96 + ci) << 10) | (size_t)(px & 1023)]);
        } break;
    }
}

// ---------------- 3x3 conv as bf16-MFMA shift-GEMM + BN + exact GELU ----------------
// OUTM 1: f32 NCHW; 2: bf16 NHWC
template<int CIN, int COUT, int NTILE, int OUTM>
__global__ __launch_bounds__(256) void conv3x3_mfma_k(
    const u16* __restrict__ Xb, const u16* __restrict__ Wt,
    const float* __restrict__ g, const float* __restrict__ b,
    const float* __restrict__ m, const float* __restrict__ v,
    void* __restrict__ out)
{
    constexpr int LDA = 40;
    constexpr int NT = NTILE / 16;
    __shared__ u16 As[64 * LDA];
    __shared__ u16 Bs[NTILE * LDA];
    const int tid = threadIdx.x;
    const int wave = tid >> 6, lane = tid & 63;
    const int quad = lane >> 4, l16 = lane & 15;
    const int rowBase = blockIdx.x * 64;
    const int colBase = blockIdx.y * NTILE;

    f32x4 acc[NT];
    #pragma unroll
    for (int nt = 0; nt < NT; ++nt)
        #pragma unroll
        for (int i = 0; i < 4; ++i) acc[nt][i] = 0.f;

    const int ar = tid >> 2, aseg = tid & 3;
    const int apx = rowBase + ar;
    const int ah = (apx >> 5) & 31, aw = apx & 31;

    for (int t = 0; t < 9; ++t) {
        const int dr = t / 3 - 1, dc = t % 3 - 1;
        const bool avalid = ((unsigned)(ah + dr) < 32u) && ((unsigned)(aw + dc) < 32u);
        const int apxs = apx + dr * 32 + dc;
        for (int ci0 = 0; ci0 < CIN; ci0 += 32) {
            __syncthreads();
            uint4 va = make_uint4(0u, 0u, 0u, 0u);
            if (avalid)
                va = *(const uint4*)(Xb + (size_t)apxs * CIN + ci0 + aseg * 8);
            *(uint4*)(As + ar * LDA + aseg * 8) = va;
            if (tid < NTILE * 4) {
                int r = tid >> 2, seg = tid & 3;
                uint4 vb = *(const uint4*)(Wt + ((size_t)t * COUT + colBase + r) * CIN + ci0 + seg * 8);
                *(uint4*)(Bs + r * LDA + seg * 8) = vb;
            }
            __syncthreads();
            short8 a = *(const short8*)(As + (wave * 16 + l16) * LDA + quad * 8);
            #pragma unroll
            for (int nt = 0; nt < NT; ++nt) {
                short8 bf = *(const short8*)(Bs + (nt * 16 + l16) * LDA + quad * 8);
                acc[nt] = __builtin_amdgcn_mfma_f32_16x16x32_bf16(a, bf, acc[nt], 0, 0, 0);
            }
        }
    }

    const int px0 = rowBase + wave * 16 + quad * 4;
    #pragma unroll
    for (int nt = 0; nt < NT; ++nt) {
        const int co = colBase + nt * 16 + l16;
        const float sc = g[co] * rsqrtf(v[co] + 1e-5f);
        const float bb = b[co] - m[co] * sc;
        float o[4];
        #pragma unroll
        for (int r = 0; r < 4; ++r) {
            float xv = acc[nt][r] * sc + bb;
            o[r] = 0.5f * xv * (1.f + erff(xv * 0.70710678f));
        }
        if (OUTM == 2) {
            #pragma unroll
            for (int r = 0; r < 4; ++r)
                ((u16*)out)[(size_t)(px0 + r) * COUT + co] = f2b(o[r]);
        } else {
            const int img = px0 >> 10, off = px0 & 1023;
            *(float4*)((float*)out + (((size_t)img * COUT + co) << 10) + off) =
                make_float4(o[0], o[1], o[2], o[3]);
        }
    }
}

// ---------------- shared MFMA GEMM body ----------------
// C[M,N] = A[M,K] @ B[N,K]^T. EPI: 0 none, 1 BN+SiLU, 2 softplus+bias, 3 SiLU.
// OUTM: 0 f32 row-major, 2 bf16 row-major, 3 f32 transposed C_t[co*M+row].
template<int NTILE, int EPI, int OUTM>
__device__ __forceinline__ void gemm_body(
    int M, int N, int K,
    const u16* __restrict__ Ab, const u16* __restrict__ Bb, void* __restrict__ C,
    const float* __restrict__ p0, const float* __restrict__ p1,
    const float* __restrict__ p2, const float* __restrict__ p3,
    int rowBase, int colBase, u16* As, u16* Bs)
{
    constexpr int LDA = 40;
    constexpr int NT = NTILE / 16;
    const int tid = threadIdx.x;
    const int wave = tid >> 6, lane = tid & 63;
    const int quad = lane >> 4, l16 = lane & 15;

    f32x4 acc[NT];
    #pragma unroll
    for (int nt = 0; nt < NT; ++nt)
        #pragma unroll
        for (int i = 0; i < 4; ++i) acc[nt][i] = 0.f;

    const int ar = tid >> 2, aseg = tid & 3;

    for (int k0 = 0; k0 < K; k0 += 32) {
        __syncthreads();
        uint4 va = *(const uint4*)(Ab + (size_t)(rowBase + ar) * K + k0 + aseg * 8);
        *(uint4*)(As + ar * LDA + aseg * 8) = va;
        if (tid < NTILE * 4) {
            int r = tid >> 2, seg = tid & 3;
            uint4 vb = *(const uint4*)(Bb + (size_t)(colBase + r) * K + k0 + seg * 8);
            *(uint4*)(Bs + r * LDA + seg * 8) = vb;
        }
        __syncthreads();
        short8 a = *(const short8*)(As + (wave * 16 + l16) * LDA + quad * 8);
        #pragma unroll
        for (int nt = 0; nt < NT; ++nt) {
            short8 bf = *(const short8*)(Bs + (nt * 16 + l16) * LDA + quad * 8);
            acc[nt] = __builtin_amdgcn_mfma_f32_16x16x32_bf16(a, bf, acc[nt], 0, 0, 0);
        }
    }

    const int px0 = rowBase + wave * 16 + quad * 4;
    #pragma unroll
    for (int nt = 0; nt < NT; ++nt) {
        const int co = colBase + nt * 16 + l16;
        float sc = 0.f, bb = 0.f;
        if (EPI == 1) {
            sc = p0[co] * rsqrtf(p3[co] + 1e-5f);
            bb = p1[co] - p2[co] * sc;
        } else if (EPI == 2) {
            bb = p0[co];
        }
        float o[4];
        #pragma unroll
        for (int r = 0; r < 4; ++r) {
            float xv = acc[nt][r];
            if (EPI == 1) {
                xv = xv * sc + bb;
                xv = xv / (1.f + __expf(-xv));
            } else if (EPI == 2) {
                xv += bb;
                xv = (xv > 20.f) ? xv : log1pf(__expf(xv));
            } else if (EPI == 3) {
                xv = xv / (1.f + __expf(-xv));
            }
            o[r] = xv;
        }
        if (OUTM == 3) {
            *(float4*)((float*)C + (size_t)co * M + px0) =
                make_float4(o[0], o[1], o[2], o[3]);
        } else if (OUTM == 2) {
            #pragma unroll
            for (int r = 0; r < 4; ++r)
                ((u16*)C)[(size_t)(px0 + r) * N + co] = f2b(o[r]);
        } else {
            #pragma unroll
            for (int r = 0; r < 4; ++r)
                ((float*)C)[(size_t)(px0 + r) * N + co] = o[r];
        }
    }
}

template<int NTILE, int EPI, int OUTM>
__global__ __launch_bounds__(256) void gemm_mfma_k(
    int M, int N, int K,
    const u16* __restrict__ Ab, const u16* __restrict__ Bb, void* __restrict__ C,
    const float* __restrict__ p0, const float* __restrict__ p1,
    const float* __restrict__ p2, const float* __restrict__ p3)
{
    __shared__ u16 As[64 * 40];
    __shared__ u16 Bs[NTILE * 40];
    gemm_body<NTILE, EPI, OUTM>(M, N, K, Ab, Bb, C, p0, p1, p2, p3,
                                blockIdx.x * 64, blockIdx.y * NTILE, As, Bs);
}

// ---------------- combined x-proj + dt dispatch ----------------
__global__ __launch_bounds__(256) void pd_k(
    const u16* __restrict__ xcb, const u16* __restrict__ Wdt,
    const u16* __restrict__ xpb, const float* __restrict__ dt_b,
    float* __restrict__ dtt, float* __restrict__ dblt)
{
    __shared__ u16 As[64 * 40];
    __shared__ u16 Bs[64 * 40];
    if (blockIdx.y < 6) {
        gemm_body<64, 2, 3>(8192, 384, 384, xcb, Wdt, dtt, dt_b, nullptr, nullptr, nullptr,
                            blockIdx.x * 64, blockIdx.y * 64, As, Bs);
    } else {
        gemm_body<32, 0, 3>(8192, 32, 384, xcb, xpb, dblt, nullptr, nullptr, nullptr, nullptr,
                            blockIdx.x * 64, 0, As, Bs);
    }
}

// ---------------- out-proj GEMM with transposed-f32 A staging ----------------
// A = At f32 [K][M]; converts to bf16 in LDS. Epilogue BN+SiLU, bf16 out.
__global__ __launch_bounds__(256) void gemm_at_k(
    int M, int N, int K,
    const float* __restrict__ At, const u16* __restrict__ Bb, u16* __restrict__ C,
    const float* __restrict__ p0, const float* __restrict__ p1,
    const float* __restrict__ p2, const float* __restrict__ p3)
{
    constexpr int LDA = 40;
    constexpr int NTILE = 64, NT = 4;
    __shared__ u16 As[64 * LDA];
    __shared__ u16 Bs[NTILE * LDA];
    const int tid = threadIdx.x;
    const int wave = tid >> 6, lane = tid & 63;
    const int quad = lane >> 4, l16 = lane & 15;
    const int rowBase = blockIdx.x * 64;
    const int colBase = blockIdx.y * NTILE;

    f32x4 acc[NT];
    #pragma unroll
    for (int nt = 0; nt < NT; ++nt)
        #pragma unroll
        for (int i = 0; i < 4; ++i) acc[nt][i] = 0.f;

    const int krow = tid >> 3, mseg = tid & 7;

    for (int k0 = 0; k0 < K; k0 += 32) {
        __syncthreads();
        const float* src = At + (size_t)(k0 + krow) * M + rowBase + mseg * 4;
        float4 f0 = *(const float4*)(src);
        float4 f1 = *(const float4*)(src + 32);
        As[(mseg*4 + 0) * LDA + krow] = f2b(f0.x);
        As[(mseg*4 + 1) * LDA + krow] = f2b(f0.y);
        As[(mseg*4 + 2) * LDA + krow] = f2b(f0.z);
        As[(mseg*4 + 3) * LDA + krow] = f2b(f0.w);
        As[(mseg*4 + 32) * LDA + krow] = f2b(f1.x);
        As[(mseg*4 + 33) * LDA + krow] = f2b(f1.y);
        As[(mseg*4 + 34) * LDA + krow] = f2b(f1.z);
        As[(mseg*4 + 35) * LDA + krow] = f2b(f1.w);
        if (tid < NTILE * 4) {
            int r = tid >> 2, seg = tid & 3;
            uint4 vb = *(const uint4*)(Bb + (size_t)(colBase + r) * K + k0 + seg * 8);
            *(uint4*)(Bs + r * LDA + seg * 8) = vb;
        }
        __syncthreads();
        short8 a = *(const short8*)(As + (wave * 16 + l16) * LDA + quad * 8);
        #pragma unroll
        for (int nt = 0; nt < NT; ++nt) {
            short8 bf = *(const short8*)(Bs + (nt * 16 + l16) * LDA + quad * 8);
            acc[nt] = __builtin_amdgcn_mfma_f32_16x16x32_bf16(a, bf, acc[nt], 0, 0, 0);
        }
    }

    const int px0 = rowBase + wave * 16 + quad * 4;
    #pragma unroll
    for (int nt = 0; nt < NT; ++nt) {
        const int co = colBase + nt * 16 + l16;
        const float sc = p0[co] * rsqrtf(p3[co] + 1e-5f);
        const float bb = p1[co] - p2[co] * sc;
        #pragma unroll
        for (int r = 0; r < 4; ++r) {
            float xv = acc[nt][r] * sc + bb;
            xv = xv / (1.f + __expf(-xv));
            C[(size_t)(px0 + r) * N + co] = f2b(xv);
        }
    }
}

// ---------------- depthwise causal conv (K=4) + SiLU ----------------
// xz: [8192][384] f32 (x half). Outputs xcb bf16 row-major + xct f32 [d][m].
__global__ __launch_bounds__(256) void dwconv_k(
    const float* __restrict__ xz, const float* __restrict__ cw, const float* __restrict__ cb,
    u16* __restrict__ xcb, float* __restrict__ xct)
{
    __shared__ float T[64][65];
    const int tid = threadIdx.x;
    const int cl = tid & 63, rq = tid >> 6;
    const int mBase = blockIdx.x * 64, cBase = blockIdx.y * 64;
    const int c = cBase + cl;
    const float w0 = cw[c*4+0], w1 = cw[c*4+1], w2 = cw[c*4+2], w3 = cw[c*4+3];
    const float bias = cb[c];
    #pragma unroll
    for (int rr = 0; rr < 16; ++rr) {
        int ml = rr * 4 + rq;
        int bl = mBase + ml;
        int l = bl & 1023;
        float acc = bias + xz[(size_t)bl * 384 + c] * w3;
        if (l >= 1) acc += xz[(size_t)(bl-1) * 384 + c] * w2;
        if (l >= 2) acc += xz[(size_t)(bl-2) * 384 + c] * w1;
        if (l >= 3) acc += xz[(size_t)(bl-3) * 384 + c] * w0;
        float s = acc / (1.f + __expf(-acc));
        xcb[(size_t)bl * DI_ + c] = f2b(s);
        T[ml][cl] = s;
    }
    __syncthreads();
    #pragma unroll
    for (int rr = 0; rr < 16; ++rr) {
        int dl = rr * 4 + rq;
        xct[(size_t)(cBase + dl) * 8192 + mBase + cl] = T[cl][dl];
    }
}

// ---------------- selective scan: LDS-combine, exp-of-sum trick ----------------
// dblt rows: 0..15 = Bs[n], 16..31 = Cs[n]. Chunk a-product = exp(And*sum(dt)).
__global__ __launch_bounds__(256) void scan_k(
    const float* __restrict__ dtt, const float* __restrict__ dblt,
    const float* __restrict__ xct, const float* __restrict__ zst,
    const float* __restrict__ A_log, const float* __restrict__ Dp,
    float* __restrict__ yft)
{
    const int bd = blockIdx.x;
    const int b = bd / DI_, d = bd % DI_;
    const int tid = threadIdx.x;
    const size_t tb = (size_t)d * 8192 + (size_t)b * 1024;
    const size_t nb = (size_t)b * 1024;
    const int t4 = tid * 4;

    __shared__ float LH[16][257];
    __shared__ float SD[257];
    __shared__ float SH[16][17];
    __shared__ float SP[16][17];
    __shared__ float SSD[17];
    __shared__ float AndS[16];

    const float4 dt4 = *(const float4*)(dtt + tb + t4);
    const float4 xc4 = *(const float4*)(xct + tb + t4);
    const float dtxc[4] = {dt4.x*xc4.x, dt4.y*xc4.y, dt4.z*xc4.z, dt4.w*xc4.w};

    float And[16];
    #pragma unroll
    for (int n = 0; n < 16; ++n) And[n] = -__expf(A_log[d*16 + n]);
    if (tid < 16) AndS[tid] = -__expf(A_log[d*16 + tid]);
    SD[tid] = dt4.x + dt4.y + dt4.z + dt4.w;

    // pass 1: local 4-step h (h_in = 0)
    #pragma unroll
    for (int n = 0; n < 16; ++n) {
        const float4 bs4 = *(const float4*)(dblt + (size_t)n * 8192 + nb + t4);
        float h = dtxc[0] * bs4.x;
        h = __expf(dt4.y * And[n]) * h + dtxc[1] * bs4.y;
        h = __expf(dt4.z * And[n]) * h + dtxc[2] * bs4.z;
        h = __expf(dt4.w * And[n]) * h + dtxc[3] * bs4.w;
        LH[n][tid] = h;
    }
    __syncthreads();

    // level A: (n, segment s) serial scan of 16 chunks
    {
        const int n = tid & 15, s = tid >> 4;
        const float An = AndS[n];
        float H = 0.f, ssd = 0.f;
        #pragma unroll
        for (int k = 0; k < 16; ++k) {
            const int c = s * 16 + k;
            float sd = SD[c];
            H = __expf(An * sd) * H + LH[n][c];
            ssd += sd;
        }
        SH[n][s] = H;
        if (n == 0) SSD[s] = ssd;
    }
    __syncthreads();

    // level B: 16 threads scan segment totals
    if (tid < 16) {
        const float An = AndS[tid];
        float Hp = 0.f;
        #pragma unroll
        for (int s = 0; s < 16; ++s) {
            SP[tid][s] = Hp;
            Hp = __expf(An * SSD[s]) * Hp + SH[tid][s];
        }
    }
    __syncthreads();

    // level A2: per-chunk exclusive h_in written back into LH
    {
        const int n = tid & 15, s = tid >> 4;
        const float An = AndS[n];
        float st = SP[n][s];
        #pragma unroll
        for (int k = 0; k < 16; ++k) {
            const int c = s * 16 + k;
            float a = __expf(An * SD[c]);
            float h = LH[n][c];
            LH[n][c] = st;
            st = a * st + h;
        }
    }
    __syncthreads();

    // pass 2: recompute with h_in, fuse y-reduce + Dp + z-gate
    float y0 = 0.f, y1 = 0.f, y2 = 0.f, y3 = 0.f;
    #pragma unroll
    for (int n = 0; n < 16; ++n) {
        float h = LH[n][tid];
        const float4 bs4 = *(const float4*)(dblt + (size_t)n * 8192 + nb + t4);
        const float4 cs4 = *(const float4*)(dblt + (size_t)(16 + n) * 8192 + nb + t4);
        h = __expf(dt4.x * And[n]) * h + dtxc[0]*bs4.x; y0 += h * cs4.x;
        h = __expf(dt4.y * And[n]) * h + dtxc[1]*bs4.y; y1 += h * cs4.y;
        h = __expf(dt4.z * And[n]) * h + dtxc[2]*bs4.z; y2 += h * cs4.z;
        h = __expf(dt4.w * And[n]) * h + dtxc[3]*bs4.w; y3 += h * cs4.w;
    }
    const float dp = Dp[d];
    const float4 zs4 = *(const float4*)(zst + tb + t4);
    float4 o;
    o.x = (y0 + xc4.x * dp) * zs4.x;
    o.y = (y1 + xc4.y * dp) * zs4.y;
    o.z = (y2 + xc4.z * dp) * zs4.z;
    o.w = (y3 + xc4.w * dp) * zs4.w;
    *(float4*)(yft + tb + t4) = o;
}

extern "C" void kernel_launch(void* const* d_in, const int* in_sizes, int n_in,
                              void* d_out, int out_size, void* d_ws, size_t ws_size,
                              hipStream_t stream) {
    const float* x     = (const float*)d_in[0];
    const float* w1    = (const float*)d_in[1];
    const float* g1    = (const float*)d_in[2];
    const float* b1    = (const float*)d_in[3];
    const float* m1    = (const float*)d_in[4];
    const float* v1    = (const float*)d_in[5];
    const float* w2    = (const float*)d_in[6];
    const float* g2    = (const float*)d_in[7];
    const float* b2    = (const float*)d_in[8];
    const float* m2    = (const float*)d_in[9];
    const float* v2    = (const float*)d_in[10];
    const float* in_w  = (const float*)d_in[11];
    const float* cw    = (const float*)d_in[12];
    const float* cb    = (const float*)d_in[13];
    const float* xp_w  = (const float*)d_in[14];
    const float* dt_w  = (const float*)d_in[15];
    const float* dt_b  = (const float*)d_in[16];
    const float* A_log = (const float*)d_in[17];
    const float* Dp    = (const float*)d_in[18];
    const float* out_w = (const float*)d_in[19];
    const float* w3    = (const float*)d_in[20];
    const float* g3    = (const float*)d_in[21];
    const float* b3    = (const float*)d_in[22];
    const float* m3    = (const float*)d_in[23];
    const float* v3    = (const float*)d_in[24];
    const float* w4    = (const float*)d_in[25];
    const float* g4    = (const float*)d_in[26];
    const float* b4    = (const float*)d_in[27];
    const float* m4    = (const float*)d_in[28];
    const float* v4    = (const float*)d_in[29];

    float* ws   = (float*)d_ws;
    float* xzb  = ws + O_XZ;
    float* xct  = ws + O_XCT;
    float* zst  = ws + O_ZST;
    float* dblt = ws + O_DBLT;
    float* yft  = ws + O_YFT;
    float* dtt  = ws + O_DTT;
    u16* b16  = (u16*)(ws + O_B16);
    u16* t1b  = b16 + B_T1;
    u16* t2b  = b16 + B_T2;
    u16* xcb  = b16 + B_XC;
    u16* Xb1  = b16 + B_XB1;
    u16* Xb4  = b16 + B_XB4;
    u16* wt1  = b16 + B_WT1;
    u16* wt4  = b16 + B_WT4;
    u16* inwb = b16 + B_INW;
    u16* w2b  = b16 + B_W2;
    u16* xpb  = b16 + B_XP;
    u16* Wdt  = b16 + B_WDT;
    u16* Wow  = b16 + B_WOW;

    // 0) weight prep + input convert (8 jobs)
    PrepArgs pa;
    pa.w1 = w1; pa.w4 = w4; pa.in_w = in_w; pa.w2 = w2; pa.xp_w = xp_w;
    pa.dt_w = dt_w; pa.w3 = w3; pa.out_w = out_w; pa.x = x;
    pa.wt1 = wt1; pa.wt4 = wt4; pa.inwb = inwb; pa.w2b = w2b; pa.xpb = xpb;
    pa.Wdt = Wdt; pa.Wow = Wow; pa.Xb1 = Xb1;
    prep_k<<<dim3(256, 8), 256, 0, stream>>>(pa);

    // 1) conv3x3 96->96 + BN + GELU -> t1 bf16 NHWC
    conv3x3_mfma_k<96, 96, 32, 2><<<dim3(128, 3), 256, 0, stream>>>(
        Xb1, wt1, g1, b1, m1, v1, t1b);

    // 2) 1x1 conv 96->192 + BN + SiLU -> t2 bf16
    gemm_mfma_k<64, 1, 2><<<dim3(128, 3), 256, 0, stream>>>(
        8192, 192, 96, t1b, w2b, t2b, g2, b2, m2, v2);

    // 3a) in-proj x-half: xz = t2 @ in_w[:384]^T  (8192,384) f32 row-major
    gemm_mfma_k<64, 0, 0><<<dim3(128, 6), 256, 0, stream>>>(
        8192, 384, 192, t2b, inwb, xzb, nullptr, nullptr, nullptr, nullptr);

    // 3b) in-proj z-half + SiLU -> zst transposed [384][8192] f32
    gemm_mfma_k<64, 3, 3><<<dim3(128, 6), 256, 0, stream>>>(
        8192, 384, 192, t2b, inwb + (size_t)384*192, zst, nullptr, nullptr, nullptr, nullptr);

    // 4) depthwise causal conv + SiLU -> xcb bf16 + xct f32 transposed
    dwconv_k<<<dim3(128, 6), 256, 0, stream>>>(xzb, cw, cb, xcb, xct);

    // 5) combined: dt (y<6) + x-proj Bs/Cs (y==6) -> dtt, dblt (both transposed)
    pd_k<<<dim3(128, 7), 256, 0, stream>>>(xcb, Wdt, xpb, dt_b, dtt, dblt);

    // 6) selective scan + gate -> yft [384][8192] f32
    scan_k<<<8 * DI_, 256, 0, stream>>>(dtt, dblt, xct, zst, A_log, Dp, yft);

    // 7) fused out-proj + 1x1 conv3 + BN + SiLU (transposed-A MFMA) -> Xb4 bf16
    gemm_at_k<<<dim3(128, 3), 256, 0, stream>>>(
        8192, 192, 384, yft, Wow, Xb4, g3, b3, m3, v3);

    // 8) conv3x3 192->192 + BN + GELU -> out f32 NCHW
    conv3x3_mfma_k<192, 192, 64, 1><<<dim3(128, 3), 256, 0, stream>>>(
        Xb4, wt4, g4, b4, m4, v4, (float*)d_out);
}

// Round 10
// 264.656 us; speedup vs baseline: 2.7545x; 1.0474x over previous
//
#include <hip/hip_runtime.h>
#include <hip/hip_bf16.h>

using u16 = unsigned short;
using short8 = __attribute__((ext_vector_type(8))) short;
using f32x4  = __attribute__((ext_vector_type(4))) float;

constexpr int DI_ = 384;

// ---- workspace layout ----
constexpr size_t O_XZ   = 0;                         // 8192*384 x-half of in-proj; later dtt
constexpr size_t O_XCT  = O_XZ  + (size_t)8192*384;  // 384*8192 xc transposed f32
constexpr size_t O_ZST  = O_XCT + (size_t)384*8192;  // 384*8192 silu(z) transposed f32
constexpr size_t O_DBLT = O_ZST + (size_t)384*8192;  // 32*8192  Bs/Cs transposed f32
constexpr size_t O_YFT  = O_DBLT+ (size_t)32*8192;   // 384*8192 scan output f32
constexpr size_t O_B16  = O_YFT + (size_t)384*8192;  // bf16 arena start
constexpr size_t O_DTT  = O_XZ;                      // overlays dead xz
// bf16 arena offsets (u16)
constexpr size_t B_T1  = 0;                          // 8192*96
constexpr size_t B_T2  = B_T1  + (size_t)8192*96;    // 8192*192
constexpr size_t B_XC  = B_T2  + (size_t)8192*192;   // 8192*384
constexpr size_t B_XB1 = B_XC  + (size_t)8192*384;   // 8192*96
constexpr size_t B_XB4 = B_XB1 + (size_t)8192*96;    // 8192*192
constexpr size_t B_WT1 = B_XB4 + (size_t)8192*192;   // 9*96*96
constexpr size_t B_WT4 = B_WT1 + (size_t)9*96*96;    // 9*192*192
constexpr size_t B_INW = B_WT4 + (size_t)9*192*192;  // 768*192
constexpr size_t B_W2  = B_INW + (size_t)768*192;    // 192*96
constexpr size_t B_XP  = B_W2  + (size_t)192*96;     // 32*384
constexpr size_t B_WDT = B_XP  + (size_t)32*384;     // 384*384
constexpr size_t B_WOW = B_WDT + (size_t)384*384;    // 192*384

__device__ __forceinline__ u16 f2b(float f) {
    __hip_bfloat16 h = __float2bfloat16(f);
    return *reinterpret_cast<u16*>(&h);
}

// ---------------- fused weight prep + input convert: 8 jobs ----------------
struct PrepArgs {
    const float *w1, *w4, *in_w, *w2, *xp_w, *dt_w, *w3, *out_w, *x;
    u16 *wt1, *wt4, *inwb, *w2b, *xpb, *Wdt, *Wow, *Xb1;
};

__global__ __launch_bounds__(256) void prep_k(PrepArgs a) {
    const int job = blockIdx.y;
    const int stride = gridDim.x * 256;
    const int i0 = blockIdx.x * 256 + threadIdx.x;
    switch (job) {
    case 0:
        for (int i = i0; i < 9*96*96; i += stride) {
            int ci = i % 96, co = (i / 96) % 96, t = i / (96*96);
            a.wt1[i] = f2b(a.w1[((size_t)co*96 + ci)*9 + t]);
        } break;
    case 1:
        for (int i = i0; i < 9*192*192; i += stride) {
            int ci = i % 192, co = (i / 192) % 192, t = i / (192*192);
            a.wt4[i] = f2b(a.w4[((size_t)co*192 + ci)*9 + t]);
        } break;
    case 2:
        for (int i = i0; i < 768*192; i += stride) a.inwb[i] = f2b(a.in_w[i]);
        break;
    case 3:
        for (int i = i0; i < 192*96; i += stride) a.w2b[i] = f2b(a.w2[i]);
        break;
    case 4: // xp_w rows 12..43 -> [32][384]
        for (int i = i0; i < 32*384; i += stride) {
            int r = i / 384, c = i % 384;
            a.xpb[i] = f2b(a.xp_w[(size_t)(12 + r)*384 + c]);
        } break;
    case 5: // Wdt = dt_w @ xp_w[:12]
        for (int i = i0; i < 384*384; i += stride) {
            int r = i / 384, c = i % 384;
            float s = 0.f;
            #pragma unroll
            for (int k = 0; k < 12; ++k) s += a.dt_w[r*12 + k] * a.xp_w[(size_t)k*384 + c];
            a.Wdt[i] = f2b(s);
        } break;
    case 6: // Wow = w3 @ out_w
        for (int i = i0; i < 192*384; i += stride) {
            int o = i / 384, d = i % 384;
            float s = 0.f;
            for (int j = 0; j < 192; ++j) s += a.w3[(size_t)o*192 + j] * a.out_w[(size_t)j*384 + d];
            a.Wow[i] = f2b(s);
        } break;
    case 7: // x NCHW f32 -> NHWC bf16
        for (int i = i0; i < 8192*96; i += stride) {
            int ci = i % 96, px = i / 96;
            a.Xb1[i] = f2b(a.x[(((size_t)(px >> 10) * 96 + ci) << 10) | (size_t)(px & 1023)]);
        } break;
    }
}

// ---------------- 3x3 conv: halo-staged bf16-MFMA + BN + exact GELU ----------------
// A staged once per ci-chunk into a zero-padded halo (4 rows x 34 cols), all 9
// taps' weights staged together: 9*NT MFMAs per barrier-pair, 3/6 barriers total.
// OUTM 1: f32 NCHW out; 2: bf16 NHWC out.
template<int CIN, int COUT, int NTILE, int OUTM>
__global__ __launch_bounds__(256) void conv3x3_mfma_k(
    const u16* __restrict__ Xb, const u16* __restrict__ Wt,
    const float* __restrict__ g, const float* __restrict__ b,
    const float* __restrict__ m, const float* __restrict__ v,
    void* __restrict__ out)
{
    constexpr int LD = 40;               // pixel/row stride in u16: 80 B -> 2-way-free banks
    constexpr int NT = NTILE / 16;
    __shared__ u16 As[4 * 36 * LD];      // halo pixels [hrow][hcol(36)][40]
    __shared__ u16 Bs[9 * NTILE * LD];   // all taps' weights
    const int tid = threadIdx.x;
    const int wave = tid >> 6, lane = tid & 63;
    const int quad = lane >> 4, l16 = lane & 15;
    const int rowBase = blockIdx.x * 64;
    const int colBase = blockIdx.y * NTILE;
    const int img = rowBase >> 10;
    const int imgRow0 = (rowBase & 1023) >> 5;   // tile covers image rows imgRow0, imgRow0+1

    // zero border cols 0 and 33 for all 4 halo rows (stay zero across chunks)
    if (tid < 160) {
        int slot8 = tid / 20;            // 0..7
        int off = tid % 20;              // uint index (2 u16 each)
        int hrow = slot8 >> 1;
        int hcol = (slot8 & 1) ? 33 : 0;
        ((unsigned*)As)[((hrow * 36 + hcol) * LD) / 2 + off] = 0u;
    }

    f32x4 acc[NT];
    #pragma unroll
    for (int nt = 0; nt < NT; ++nt)
        #pragma unroll
        for (int i = 0; i < 4; ++i) acc[nt][i] = 0.f;

    const int pxl = wave * 16 + l16;
    const int prow = pxl >> 5, pcol = pxl & 31;

    for (int ci0 = 0; ci0 < CIN; ci0 += 32) {
        __syncthreads();
        // stage A: 128 halo pixels x 4 uint4 segs (zeros for out-of-image rows)
        #pragma unroll
        for (int it = 0; it < 2; ++it) {
            int id = tid + it * 256;
            int pix = id >> 2, seg = id & 3;
            int hrow = pix >> 5, hcol = pix & 31;
            int grow = imgRow0 - 1 + hrow;
            uint4 va = make_uint4(0u, 0u, 0u, 0u);
            if ((unsigned)grow < 32u)
                va = *(const uint4*)(Xb +
                    (size_t)((img << 10) + (grow << 5) + hcol) * CIN + ci0 + seg * 8);
            *(uint4*)(As + (hrow * 36 + hcol + 1) * LD + seg * 8) = va;
        }
        // stage B: 9 taps x NTILE x 4 segs
        constexpr int BT = 9 * NTILE * 4;
        for (int id = tid; id < BT; id += 256) {
            int t = id / (NTILE * 4);
            int r = (id >> 2) & (NTILE - 1);
            int seg = id & 3;
            uint4 vb = *(const uint4*)(Wt +
                ((size_t)t * COUT + colBase + r) * CIN + ci0 + seg * 8);
            *(uint4*)(Bs + (t * NTILE + r) * LD + seg * 8) = vb;
        }
        __syncthreads();
        #pragma unroll
        for (int t = 0; t < 9; ++t) {
            const int dr = t / 3 - 1, dc = t % 3 - 1;
            short8 a = *(const short8*)(As +
                ((prow + 1 + dr) * 36 + (pcol + 1 + dc)) * LD + quad * 8);
            #pragma unroll
            for (int nt = 0; nt < NT; ++nt) {
                short8 bf = *(const short8*)(Bs + (t * NTILE + nt * 16 + l16) * LD + quad * 8);
                acc[nt] = __builtin_amdgcn_mfma_f32_16x16x32_bf16(a, bf, acc[nt], 0, 0, 0);
            }
        }
    }

    const int px0 = rowBase + wave * 16 + quad * 4;
    #pragma unroll
    for (int nt = 0; nt < NT; ++nt) {
        const int co = colBase + nt * 16 + l16;
        const float sc = g[co] * rsqrtf(v[co] + 1e-5f);
        const float bb = b[co] - m[co] * sc;
        float o[4];
        #pragma unroll
        for (int r = 0; r < 4; ++r) {
            float xv = acc[nt][r] * sc + bb;
            o[r] = 0.5f * xv * (1.f + erff(xv * 0.70710678f));
        }
        if (OUTM == 2) {
            #pragma unroll
            for (int r = 0; r < 4; ++r)
                ((u16*)out)[(size_t)(px0 + r) * COUT + co] = f2b(o[r]);
        } else {
            const int oimg = px0 >> 10, off = px0 & 1023;
            *(float4*)((float*)out + (((size_t)oimg * COUT + co) << 10) + off) =
                make_float4(o[0], o[1], o[2], o[3]);
        }
    }
}

// ---------------- shared MFMA GEMM body ----------------
// C[M,N] = A[M,K] @ B[N,K]^T. EPI: 0 none, 1 BN+SiLU, 2 softplus+bias, 3 SiLU.
// OUTM: 0 f32 row-major, 2 bf16 row-major, 3 f32 transposed C_t[co*M+row].
template<int NTILE, int EPI, int OUTM>
__device__ __forceinline__ void gemm_body(
    int M, int N, int K,
    const u16* __restrict__ Ab, const u16* __restrict__ Bb, void* __restrict__ C,
    const float* __restrict__ p0, const float* __restrict__ p1,
    const float* __restrict__ p2, const float* __restrict__ p3,
    int rowBase, int colBase, u16* As, u16* Bs)
{
    constexpr int LDA = 40;
    constexpr int NT = NTILE / 16;
    const int tid = threadIdx.x;
    const int wave = tid >> 6, lane = tid & 63;
    const int quad = lane >> 4, l16 = lane & 15;

    f32x4 acc[NT];
    #pragma unroll
    for (int nt = 0; nt < NT; ++nt)
        #pragma unroll
        for (int i = 0; i < 4; ++i) acc[nt][i] = 0.f;

    const int ar = tid >> 2, aseg = tid & 3;

    for (int k0 = 0; k0 < K; k0 += 32) {
        __syncthreads();
        uint4 va = *(const uint4*)(Ab + (size_t)(rowBase + ar) * K + k0 + aseg * 8);
        *(uint4*)(As + ar * LDA + aseg * 8) = va;
        if (tid < NTILE * 4) {
            int r = tid >> 2, seg = tid & 3;
            uint4 vb = *(const uint4*)(Bb + (size_t)(colBase + r) * K + k0 + seg * 8);
            *(uint4*)(Bs + r * LDA + seg * 8) = vb;
        }
        __syncthreads();
        short8 a = *(const short8*)(As + (wave * 16 + l16) * LDA + quad * 8);
        #pragma unroll
        for (int nt = 0; nt < NT; ++nt) {
            short8 bf = *(const short8*)(Bs + (nt * 16 + l16) * LDA + quad * 8);
            acc[nt] = __builtin_amdgcn_mfma_f32_16x16x32_bf16(a, bf, acc[nt], 0, 0, 0);
        }
    }

    const int px0 = rowBase + wave * 16 + quad * 4;
    #pragma unroll
    for (int nt = 0; nt < NT; ++nt) {
        const int co = colBase + nt * 16 + l16;
        float sc = 0.f, bb = 0.f;
        if (EPI == 1) {
            sc = p0[co] * rsqrtf(p3[co] + 1e-5f);
            bb = p1[co] - p2[co] * sc;
        } else if (EPI == 2) {
            bb = p0[co];
        }
        float o[4];
        #pragma unroll
        for (int r = 0; r < 4; ++r) {
            float xv = acc[nt][r];
            if (EPI == 1) {
                xv = xv * sc + bb;
                xv = xv / (1.f + __expf(-xv));
            } else if (EPI == 2) {
                xv += bb;
                xv = (xv > 20.f) ? xv : log1pf(__expf(xv));
            } else if (EPI == 3) {
                xv = xv / (1.f + __expf(-xv));
            }
            o[r] = xv;
        }
        if (OUTM == 3) {
            *(float4*)((float*)C + (size_t)co * M + px0) =
                make_float4(o[0], o[1], o[2], o[3]);
        } else if (OUTM == 2) {
            #pragma unroll
            for (int r = 0; r < 4; ++r)
                ((u16*)C)[(size_t)(px0 + r) * N + co] = f2b(o[r]);
        } else {
            #pragma unroll
            for (int r = 0; r < 4; ++r)
                ((float*)C)[(size_t)(px0 + r) * N + co] = o[r];
        }
    }
}

template<int NTILE, int EPI, int OUTM>
__global__ __launch_bounds__(256) void gemm_mfma_k(
    int M, int N, int K,
    const u16* __restrict__ Ab, const u16* __restrict__ Bb, void* __restrict__ C,
    const float* __restrict__ p0, const float* __restrict__ p1,
    const float* __restrict__ p2, const float* __restrict__ p3)
{
    __shared__ u16 As[64 * 40];
    __shared__ u16 Bs[NTILE * 40];
    gemm_body<NTILE, EPI, OUTM>(M, N, K, Ab, Bb, C, p0, p1, p2, p3,
                                blockIdx.x * 64, blockIdx.y * NTILE, As, Bs);
}

// ---------------- combined in-proj dispatch: x-half (y<6) + z-half (y>=6) ----------------
__global__ __launch_bounds__(256) void ip_k(
    const u16* __restrict__ t2b, const u16* __restrict__ inwb,
    float* __restrict__ xzb, float* __restrict__ zst)
{
    __shared__ u16 As[64 * 40];
    __shared__ u16 Bs[64 * 40];
    if (blockIdx.y < 6) {
        gemm_body<64, 0, 0>(8192, 384, 192, t2b, inwb, xzb,
                            nullptr, nullptr, nullptr, nullptr,
                            blockIdx.x * 64, blockIdx.y * 64, As, Bs);
    } else {
        gemm_body<64, 3, 3>(8192, 384, 192, t2b, inwb + (size_t)384*192, zst,
                            nullptr, nullptr, nullptr, nullptr,
                            blockIdx.x * 64, (blockIdx.y - 6) * 64, As, Bs);
    }
}

// ---------------- combined x-proj + dt dispatch ----------------
__global__ __launch_bounds__(256) void pd_k(
    const u16* __restrict__ xcb, const u16* __restrict__ Wdt,
    const u16* __restrict__ xpb, const float* __restrict__ dt_b,
    float* __restrict__ dtt, float* __restrict__ dblt)
{
    __shared__ u16 As[64 * 40];
    __shared__ u16 Bs[64 * 40];
    if (blockIdx.y < 6) {
        gemm_body<64, 2, 3>(8192, 384, 384, xcb, Wdt, dtt, dt_b, nullptr, nullptr, nullptr,
                            blockIdx.x * 64, blockIdx.y * 64, As, Bs);
    } else {
        gemm_body<32, 0, 3>(8192, 32, 384, xcb, xpb, dblt, nullptr, nullptr, nullptr, nullptr,
                            blockIdx.x * 64, 0, As, Bs);
    }
}

// ---------------- out-proj GEMM with transposed-f32 A staging ----------------
__global__ __launch_bounds__(256) void gemm_at_k(
    int M, int N, int K,
    const float* __restrict__ At, const u16* __restrict__ Bb, u16* __restrict__ C,
    const float* __restrict__ p0, const float* __restrict__ p1,
    const float* __restrict__ p2, const float* __restrict__ p3)
{
    constexpr int LDA = 40;
    constexpr int NTILE = 64, NT = 4;
    __shared__ u16 As[64 * LDA];
    __shared__ u16 Bs[NTILE * LDA];
    const int tid = threadIdx.x;
    const int wave = tid >> 6, lane = tid & 63;
    const int quad = lane >> 4, l16 = lane & 15;
    const int rowBase = blockIdx.x * 64;
    const int colBase = blockIdx.y * NTILE;

    f32x4 acc[NT];
    #pragma unroll
    for (int nt = 0; nt < NT; ++nt)
        #pragma unroll
        for (int i = 0; i < 4; ++i) acc[nt][i] = 0.f;

    const int krow = tid >> 3, mseg = tid & 7;

    for (int k0 = 0; k0 < K; k0 += 32) {
        __syncthreads();
        const float* src = At + (size_t)(k0 + krow) * M + rowBase + mseg * 4;
        float4 f0 = *(const float4*)(src);
        float4 f1 = *(const float4*)(src + 32);
        As[(mseg*4 + 0) * LDA + krow] = f2b(f0.x);
        As[(mseg*4 + 1) * LDA + krow] = f2b(f0.y);
        As[(mseg*4 + 2) * LDA + krow] = f2b(f0.z);
        As[(mseg*4 + 3) * LDA + krow] = f2b(f0.w);
        As[(mseg*4 + 32) * LDA + krow] = f2b(f1.x);
        As[(mseg*4 + 33) * LDA + krow] = f2b(f1.y);
        As[(mseg*4 + 34) * LDA + krow] = f2b(f1.z);
        As[(mseg*4 + 35) * LDA + krow] = f2b(f1.w);
        if (tid < NTILE * 4) {
            int r = tid >> 2, seg = tid & 3;
            uint4 vb = *(const uint4*)(Bb + (size_t)(colBase + r) * K + k0 + seg * 8);
            *(uint4*)(Bs + r * LDA + seg * 8) = vb;
        }
        __syncthreads();
        short8 a = *(const short8*)(As + (wave * 16 + l16) * LDA + quad * 8);
        #pragma unroll
        for (int nt = 0; nt < NT; ++nt) {
            short8 bf = *(const short8*)(Bs + (nt * 16 + l16) * LDA + quad * 8);
            acc[nt] = __builtin_amdgcn_mfma_f32_16x16x32_bf16(a, bf, acc[nt], 0, 0, 0);
        }
    }

    const int px0 = rowBase + wave * 16 + quad * 4;
    #pragma unroll
    for (int nt = 0; nt < NT; ++nt) {
        const int co = colBase + nt * 16 + l16;
        const float sc = p0[co] * rsqrtf(p3[co] + 1e-5f);
        const float bb = p1[co] - p2[co] * sc;
        #pragma unroll
        for (int r = 0; r < 4; ++r) {
            float xv = acc[nt][r] * sc + bb;
            xv = xv / (1.f + __expf(-xv));
            C[(size_t)(px0 + r) * N + co] = f2b(xv);
        }
    }
}

// ---------------- depthwise causal conv (K=4) + SiLU ----------------
__global__ __launch_bounds__(256) void dwconv_k(
    const float* __restrict__ xz, const float* __restrict__ cw, const float* __restrict__ cb,
    u16* __restrict__ xcb, float* __restrict__ xct)
{
    __shared__ float T[64][65];
    const int tid = threadIdx.x;
    const int cl = tid & 63, rq = tid >> 6;
    const int mBase = blockIdx.x * 64, cBase = blockIdx.y * 64;
    const int c = cBase + cl;
    const float w0 = cw[c*4+0], w1 = cw[c*4+1], w2 = cw[c*4+2], w3 = cw[c*4+3];
    const float bias = cb[c];
    #pragma unroll
    for (int rr = 0; rr < 16; ++rr) {
        int ml = rr * 4 + rq;
        int bl = mBase + ml;
        int l = bl & 1023;
        float acc = bias + xz[(size_t)bl * 384 + c] * w3;
        if (l >= 1) acc += xz[(size_t)(bl-1) * 384 + c] * w2;
        if (l >= 2) acc += xz[(size_t)(bl-2) * 384 + c] * w1;
        if (l >= 3) acc += xz[(size_t)(bl-3) * 384 + c] * w0;
        float s = acc / (1.f + __expf(-acc));
        xcb[(size_t)bl * DI_ + c] = f2b(s);
        T[ml][cl] = s;
    }
    __syncthreads();
    #pragma unroll
    for (int rr = 0; rr < 16; ++rr) {
        int dl = rr * 4 + rq;
        xct[(size_t)(cBase + dl) * 8192 + mBase + cl] = T[cl][dl];
    }
}

// ---------------- selective scan: LDS-combine, exp-of-sum trick ----------------
__global__ __launch_bounds__(256) void scan_k(
    const float* __restrict__ dtt, const float* __restrict__ dblt,
    const float* __restrict__ xct, const float* __restrict__ zst,
    const float* __restrict__ A_log, const float* __restrict__ Dp,
    float* __restrict__ yft)
{
    const int bd = blockIdx.x;
    const int b = bd / DI_, d = bd % DI_;
    const int tid = threadIdx.x;
    const size_t tb = (size_t)d * 8192 + (size_t)b * 1024;
    const size_t nb = (size_t)b * 1024;
    const int t4 = tid * 4;

    __shared__ float LH[16][257];
    __shared__ float SD[257];
    __shared__ float SH[16][17];
    __shared__ float SP[16][17];
    __shared__ float SSD[17];
    __shared__ float AndS[16];

    const float4 dt4 = *(const float4*)(dtt + tb + t4);
    const float4 xc4 = *(const float4*)(xct + tb + t4);
    const float dtxc[4] = {dt4.x*xc4.x, dt4.y*xc4.y, dt4.z*xc4.z, dt4.w*xc4.w};

    float And[16];
    #pragma unroll
    for (int n = 0; n < 16; ++n) And[n] = -__expf(A_log[d*16 + n]);
    if (tid < 16) AndS[tid] = -__expf(A_log[d*16 + tid]);
    SD[tid] = dt4.x + dt4.y + dt4.z + dt4.w;

    #pragma unroll
    for (int n = 0; n < 16; ++n) {
        const float4 bs4 = *(const float4*)(dblt + (size_t)n * 8192 + nb + t4);
        float h = dtxc[0] * bs4.x;
        h = __expf(dt4.y * And[n]) * h + dtxc[1] * bs4.y;
        h = __expf(dt4.z * And[n]) * h + dtxc[2] * bs4.z;
        h = __expf(dt4.w * And[n]) * h + dtxc[3] * bs4.w;
        LH[n][tid] = h;
    }
    __syncthreads();

    {
        const int n = tid & 15, s = tid >> 4;
        const float An = AndS[n];
        float H = 0.f, ssd = 0.f;
        #pragma unroll
        for (int k = 0; k < 16; ++k) {
            const int c = s * 16 + k;
            float sd = SD[c];
            H = __expf(An * sd) * H + LH[n][c];
            ssd += sd;
        }
        SH[n][s] = H;
        if (n == 0) SSD[s] = ssd;
    }
    __syncthreads();

    if (tid < 16) {
        const float An = AndS[tid];
        float Hp = 0.f;
        #pragma unroll
        for (int s = 0; s < 16; ++s) {
            SP[tid][s] = Hp;
            Hp = __expf(An * SSD[s]) * Hp + SH[tid][s];
        }
    }
    __syncthreads();

    {
        const int n = tid & 15, s = tid >> 4;
        const float An = AndS[n];
        float st = SP[n][s];
        #pragma unroll
        for (int k = 0; k < 16; ++k) {
            const int c = s * 16 + k;
            float a = __expf(An * SD[c]);
            float h = LH[n][c];
            LH[n][c] = st;
            st = a * st + h;
        }
    }
    __syncthreads();

    float y0 = 0.f, y1 = 0.f, y2 = 0.f, y3 = 0.f;
    #pragma unroll
    for (int n = 0; n < 16; ++n) {
        float h = LH[n][tid];
        const float4 bs4 = *(const float4*)(dblt + (size_t)n * 8192 + nb + t4);
        const float4 cs4 = *(const float4*)(dblt + (size_t)(16 + n) * 8192 + nb + t4);
        h = __expf(dt4.x * And[n]) * h + dtxc[0]*bs4.x; y0 += h * cs4.x;
        h = __expf(dt4.y * And[n]) * h + dtxc[1]*bs4.y; y1 += h * cs4.y;
        h = __expf(dt4.z * And[n]) * h + dtxc[2]*bs4.z; y2 += h * cs4.z;
        h = __expf(dt4.w * And[n]) * h + dtxc[3]*bs4.w; y3 += h * cs4.w;
    }
    const float dp = Dp[d];
    const float4 zs4 = *(const float4*)(zst + tb + t4);
    float4 o;
    o.x = (y0 + xc4.x * dp) * zs4.x;
    o.y = (y1 + xc4.y * dp) * zs4.y;
    o.z = (y2 + xc4.z * dp) * zs4.z;
    o.w = (y3 + xc4.w * dp) * zs4.w;
    *(float4*)(yft + tb + t4) = o;
}

extern "C" void kernel_launch(void* const* d_in, const int* in_sizes, int n_in,
                              void* d_out, int out_size, void* d_ws, size_t ws_size,
                              hipStream_t stream) {
    const float* x     = (const float*)d_in[0];
    const float* w1    = (const float*)d_in[1];
    const float* g1    = (const float*)d_in[2];
    const float* b1    = (const float*)d_in[3];
    const float* m1    = (const float*)d_in[4];
    const float* v1    = (const float*)d_in[5];
    const float* w2    = (const float*)d_in[6];
    const float* g2    = (const float*)d_in[7];
    const float* b2    = (const float*)d_in[8];
    const float* m2    = (const float*)d_in[9];
    const float* v2    = (const float*)d_in[10];
    const float* in_w  = (const float*)d_in[11];
    const float* cw    = (const float*)d_in[12];
    const float* cb    = (const float*)d_in[13];
    const float* xp_w  = (const float*)d_in[14];
    const float* dt_w  = (const float*)d_in[15];
    const float* dt_b  = (const float*)d_in[16];
    const float* A_log = (const float*)d_in[17];
    const float* Dp    = (const float*)d_in[18];
    const float* out_w = (const float*)d_in[19];
    const float* w3    = (const float*)d_in[20];
    const float* g3    = (const float*)d_in[21];
    const float* b3    = (const float*)d_in[22];
    const float* m3    = (const float*)d_in[23];
    const float* v3    = (const float*)d_in[24];
    const float* w4    = (const float*)d_in[25];
    const float* g4    = (const float*)d_in[26];
    const float* b4    = (const float*)d_in[27];
    const float* m4    = (const float*)d_in[28];
    const float* v4    = (const float*)d_in[29];

    float* ws   = (float*)d_ws;
    float* xzb  = ws + O_XZ;
    float* xct  = ws + O_XCT;
    float* zst  = ws + O_ZST;
    float* dblt = ws + O_DBLT;
    float* yft  = ws + O_YFT;
    float* dtt  = ws + O_DTT;
    u16* b16  = (u16*)(ws + O_B16);
    u16* t1b  = b16 + B_T1;
    u16* t2b  = b16 + B_T2;
    u16* xcb  = b16 + B_XC;
    u16* Xb1  = b16 + B_XB1;
    u16* Xb4  = b16 + B_XB4;
    u16* wt1  = b16 + B_WT1;
    u16* wt4  = b16 + B_WT4;
    u16* inwb = b16 + B_INW;
    u16* w2b  = b16 + B_W2;
    u16* xpb  = b16 + B_XP;
    u16* Wdt  = b16 + B_WDT;
    u16* Wow  = b16 + B_WOW;

    // 0) weight prep + input convert (8 jobs)
    PrepArgs pa;
    pa.w1 = w1; pa.w4 = w4; pa.in_w = in_w; pa.w2 = w2; pa.xp_w = xp_w;
    pa.dt_w = dt_w; pa.w3 = w3; pa.out_w = out_w; pa.x = x;
    pa.wt1 = wt1; pa.wt4 = wt4; pa.inwb = inwb; pa.w2b = w2b; pa.xpb = xpb;
    pa.Wdt = Wdt; pa.Wow = Wow; pa.Xb1 = Xb1;
    prep_k<<<dim3(256, 8), 256, 0, stream>>>(pa);

    // 1) conv3x3 96->96 + BN + GELU (halo MFMA) -> t1 bf16 NHWC
    conv3x3_mfma_k<96, 96, 32, 2><<<dim3(128, 3), 256, 0, stream>>>(
        Xb1, wt1, g1, b1, m1, v1, t1b);

    // 2) 1x1 conv 96->192 + BN + SiLU -> t2 bf16
    gemm_mfma_k<64, 1, 2><<<dim3(128, 3), 256, 0, stream>>>(
        8192, 192, 96, t1b, w2b, t2b, g2, b2, m2, v2);

    // 3) in-proj both halves: x-half -> xzb row-major; z-half + SiLU -> zst transposed
    ip_k<<<dim3(128, 12), 256, 0, stream>>>(t2b, inwb, xzb, zst);

    // 4) depthwise causal conv + SiLU -> xcb bf16 + xct f32 transposed
    dwconv_k<<<dim3(128, 6), 256, 0, stream>>>(xzb, cw, cb, xcb, xct);

    // 5) combined: dt (y<6) + x-proj Bs/Cs (y==6) -> dtt, dblt (both transposed)
    pd_k<<<dim3(128, 7), 256, 0, stream>>>(xcb, Wdt, xpb, dt_b, dtt, dblt);

    // 6) selective scan + gate -> yft [384][8192] f32
    scan_k<<<8 * DI_, 256, 0, stream>>>(dtt, dblt, xct, zst, A_log, Dp, yft);

    // 7) fused out-proj + 1x1 conv3 + BN + SiLU (transposed-A MFMA) -> Xb4 bf16
    gemm_at_k<<<dim3(128, 3), 256, 0, stream>>>(
        8192, 192, 384, yft, Wow, Xb4, g3, b3, m3, v3);

    // 8) conv3x3 192->192 + BN + GELU (halo MFMA) -> out f32 NCHW
    conv3x3_mfma_k<192, 192, 64, 1><<<dim3(128, 3), 256, 0, stream>>>(
        Xb4, wt4, g4, b4, m4, v4, (float*)d_out);
}

// Round 11
// 250.360 us; speedup vs baseline: 2.9118x; 1.0571x over previous
//
#include <hip/hip_runtime.h>
#include <hip/hip_bf16.h>

using u16 = unsigned short;
using short8 = __attribute__((ext_vector_type(8))) short;
using f32x4  = __attribute__((ext_vector_type(4))) float;

constexpr int DI_ = 384;

// ---- workspace layout ----
constexpr size_t O_XZ   = 0;                         // xz bf16 (8192*384 u16); later dtt f32
constexpr size_t O_XCT  = O_XZ  + (size_t)8192*384;  // xct bf16 [384][8192] u16 (region sized f32)
constexpr size_t O_ZST  = O_XCT + (size_t)384*8192;  // zst bf16 [384][8192] u16
constexpr size_t O_DBLT = O_ZST + (size_t)384*8192;  // 32*8192  Bs/Cs transposed f32
constexpr size_t O_YFT  = O_DBLT+ (size_t)32*8192;   // 384*8192 scan output f32
constexpr size_t O_B16  = O_YFT + (size_t)384*8192;  // bf16 arena start
constexpr size_t O_DTT  = O_XZ;                      // overlays dead xz
// bf16 arena offsets (u16)
constexpr size_t B_T1  = 0;                          // 8192*96
constexpr size_t B_T2  = B_T1  + (size_t)8192*96;    // 8192*192
constexpr size_t B_XC  = B_T2  + (size_t)8192*192;   // 8192*384
constexpr size_t B_XB1 = B_XC  + (size_t)8192*384;   // 8192*96
constexpr size_t B_XB4 = B_XB1 + (size_t)8192*96;    // 8192*192
constexpr size_t B_WT1 = B_XB4 + (size_t)8192*192;   // 9*96*96
constexpr size_t B_WT4 = B_WT1 + (size_t)9*96*96;    // 9*192*192
constexpr size_t B_INW = B_WT4 + (size_t)9*192*192;  // 768*192
constexpr size_t B_W2  = B_INW + (size_t)768*192;    // 192*96
constexpr size_t B_XP  = B_W2  + (size_t)192*96;     // 32*384
constexpr size_t B_WDT = B_XP  + (size_t)32*384;     // 384*384
constexpr size_t B_WOW = B_WDT + (size_t)384*384;    // 192*384

__device__ __forceinline__ u16 f2b(float f) {
    __hip_bfloat16 h = __float2bfloat16(f);
    return *reinterpret_cast<u16*>(&h);
}
__device__ __forceinline__ float b2f(u16 u) {
    return __uint_as_float(((unsigned)u) << 16);
}
__device__ __forceinline__ float b2f_lo(unsigned u) { return __uint_as_float(u << 16); }
__device__ __forceinline__ float b2f_hi(unsigned u) { return __uint_as_float(u & 0xffff0000u); }

// ---------------- fused weight prep + input convert: 8 jobs ----------------
struct PrepArgs {
    const float *w1, *w4, *in_w, *w2, *xp_w, *dt_w, *w3, *out_w, *x;
    u16 *wt1, *wt4, *inwb, *w2b, *xpb, *Wdt, *Wow, *Xb1;
};

__global__ __launch_bounds__(256) void prep_k(PrepArgs a) {
    const int job = blockIdx.y;
    const int stride = gridDim.x * 256;
    const int i0 = blockIdx.x * 256 + threadIdx.x;
    switch (job) {
    case 0:
        for (int i = i0; i < 9*96*96; i += stride) {
            int ci = i % 96, co = (i / 96) % 96, t = i / (96*96);
            a.wt1[i] = f2b(a.w1[((size_t)co*96 + ci)*9 + t]);
        } break;
    case 1:
        for (int i = i0; i < 9*192*192; i += stride) {
            int ci = i % 192, co = (i / 192) % 192, t = i / (192*192);
            a.wt4[i] = f2b(a.w4[((size_t)co*192 + ci)*9 + t]);
        } break;
    case 2:
        for (int i = i0; i < 768*192; i += stride) a.inwb[i] = f2b(a.in_w[i]);
        break;
    case 3:
        for (int i = i0; i < 192*96; i += stride) a.w2b[i] = f2b(a.w2[i]);
        break;
    case 4: // xp_w rows 12..43 -> [32][384]
        for (int i = i0; i < 32*384; i += stride) {
            int r = i / 384, c = i % 384;
            a.xpb[i] = f2b(a.xp_w[(size_t)(12 + r)*384 + c]);
        } break;
    case 5: // Wdt = dt_w @ xp_w[:12]
        for (int i = i0; i < 384*384; i += stride) {
            int r = i / 384, c = i % 384;
            float s = 0.f;
            #pragma unroll
            for (int k = 0; k < 12; ++k) s += a.dt_w[r*12 + k] * a.xp_w[(size_t)k*384 + c];
            a.Wdt[i] = f2b(s);
        } break;
    case 6: // Wow = w3 @ out_w
        for (int i = i0; i < 192*384; i += stride) {
            int o = i / 384, d = i % 384;
            float s = 0.f;
            for (int j = 0; j < 192; ++j) s += a.w3[(size_t)o*192 + j] * a.out_w[(size_t)j*384 + d];
            a.Wow[i] = f2b(s);
        } break;
    case 7: // x NCHW f32 -> NHWC bf16
        for (int i = i0; i < 8192*96; i += stride) {
            int ci = i % 96, px = i / 96;
            a.Xb1[i] = f2b(a.x[(((size_t)(px >> 10) * 96 + ci) << 10) | (size_t)(px & 1023)]);
        } break;
    }
}

// ---------------- 3x3 conv: halo-staged bf16-MFMA + BN + exact GELU ----------------
// OUTM 1: f32 NCHW out (LDS-transposed, coalesced); 2: bf16 NHWC out.
template<int CIN, int COUT, int NTILE, int OUTM>
__global__ __launch_bounds__(256) void conv3x3_mfma_k(
    const u16* __restrict__ Xb, const u16* __restrict__ Wt,
    const float* __restrict__ g, const float* __restrict__ b,
    const float* __restrict__ m, const float* __restrict__ v,
    void* __restrict__ out)
{
    constexpr int LD = 40;
    constexpr int NT = NTILE / 16;
    __shared__ u16 As[4 * 36 * LD];
    __shared__ u16 Bs[9 * NTILE * LD];
    const int tid = threadIdx.x;
    const int wave = tid >> 6, lane = tid & 63;
    const int quad = lane >> 4, l16 = lane & 15;
    const int rowBase = blockIdx.x * 64;
    const int colBase = blockIdx.y * NTILE;
    const int img = rowBase >> 10;
    const int imgRow0 = (rowBase & 1023) >> 5;

    if (tid < 160) {
        int slot8 = tid / 20;
        int off = tid % 20;
        int hrow = slot8 >> 1;
        int hcol = (slot8 & 1) ? 33 : 0;
        ((unsigned*)As)[((hrow * 36 + hcol) * LD) / 2 + off] = 0u;
    }

    f32x4 acc[NT];
    #pragma unroll
    for (int nt = 0; nt < NT; ++nt)
        #pragma unroll
        for (int i = 0; i < 4; ++i) acc[nt][i] = 0.f;

    const int pxl = wave * 16 + l16;
    const int prow = pxl >> 5, pcol = pxl & 31;

    for (int ci0 = 0; ci0 < CIN; ci0 += 32) {
        __syncthreads();
        #pragma unroll
        for (int it = 0; it < 2; ++it) {
            int id = tid + it * 256;
            int pix = id >> 2, seg = id & 3;
            int hrow = pix >> 5, hcol = pix & 31;
            int grow = imgRow0 - 1 + hrow;
            uint4 va = make_uint4(0u, 0u, 0u, 0u);
            if ((unsigned)grow < 32u)
                va = *(const uint4*)(Xb +
                    (size_t)((img << 10) + (grow << 5) + hcol) * CIN + ci0 + seg * 8);
            *(uint4*)(As + (hrow * 36 + hcol + 1) * LD + seg * 8) = va;
        }
        constexpr int BT = 9 * NTILE * 4;
        for (int id = tid; id < BT; id += 256) {
            int t = id / (NTILE * 4);
            int r = (id >> 2) & (NTILE - 1);
            int seg = id & 3;
            uint4 vb = *(const uint4*)(Wt +
                ((size_t)t * COUT + colBase + r) * CIN + ci0 + seg * 8);
            *(uint4*)(Bs + (t * NTILE + r) * LD + seg * 8) = vb;
        }
        __syncthreads();
        #pragma unroll
        for (int t = 0; t < 9; ++t) {
            const int dr = t / 3 - 1, dc = t % 3 - 1;
            short8 a = *(const short8*)(As +
                ((prow + 1 + dr) * 36 + (pcol + 1 + dc)) * LD + quad * 8);
            #pragma unroll
            for (int nt = 0; nt < NT; ++nt) {
                short8 bf = *(const short8*)(Bs + (t * NTILE + nt * 16 + l16) * LD + quad * 8);
                acc[nt] = __builtin_amdgcn_mfma_f32_16x16x32_bf16(a, bf, acc[nt], 0, 0, 0);
            }
        }
    }

    const int px0 = rowBase + wave * 16 + quad * 4;
    if (OUTM == 2) {
        #pragma unroll
        for (int nt = 0; nt < NT; ++nt) {
            const int co = colBase + nt * 16 + l16;
            const float sc = g[co] * rsqrtf(v[co] + 1e-5f);
            const float bb = b[co] - m[co] * sc;
            #pragma unroll
            for (int r = 0; r < 4; ++r) {
                float xv = acc[nt][r] * sc + bb;
                float gel = 0.5f * xv * (1.f + erff(xv * 0.70710678f));
                ((u16*)out)[(size_t)(px0 + r) * COUT + co] = f2b(gel);
            }
        }
    } else {
        // stage tile [NTILE co][64 px] in LDS (pad 68), then coalesced NCHW writes
        float* Tout = (float*)As;   // NTILE*68*4 <= 11520 B for NTILE=32
        const int pxl0 = wave * 16 + quad * 4;
        __syncthreads();
        #pragma unroll
        for (int nt = 0; nt < NT; ++nt) {
            const int co = colBase + nt * 16 + l16;
            const float sc = g[co] * rsqrtf(v[co] + 1e-5f);
            const float bb = b[co] - m[co] * sc;
            #pragma unroll
            for (int r = 0; r < 4; ++r) {
                float xv = acc[nt][r] * sc + bb;
                Tout[(nt * 16 + l16) * 68 + pxl0 + r] =
                    0.5f * xv * (1.f + erff(xv * 0.70710678f));
            }
        }
        __syncthreads();
        const int off0 = rowBase & 1023;
        for (int s = tid; s < NTILE * 16; s += 256) {
            int co = s >> 4, p4 = s & 15;
            float4 vv = *(const float4*)(Tout + co * 68 + p4 * 4);
            *(float4*)((float*)out + (((size_t)img * COUT + colBase + co) << 10)
                       + off0 + p4 * 4) = vv;
        }
    }
}

// ---------------- shared MFMA GEMM body ----------------
// EPI: 0 none, 1 BN+SiLU, 2 softplus+bias, 3 SiLU.
// OUTM: 0 f32 row-major, 2 bf16 row-major, 3 f32 transposed, 4 bf16 transposed.
template<int NTILE, int EPI, int OUTM>
__device__ __forceinline__ void gemm_body(
    int M, int N, int K,
    const u16* __restrict__ Ab, const u16* __restrict__ Bb, void* __restrict__ C,
    const float* __restrict__ p0, const float* __restrict__ p1,
    const float* __restrict__ p2, const float* __restrict__ p3,
    int rowBase, int colBase, u16* As, u16* Bs)
{
    constexpr int LDA = 40;
    constexpr int NT = NTILE / 16;
    const int tid = threadIdx.x;
    const int wave = tid >> 6, lane = tid & 63;
    const int quad = lane >> 4, l16 = lane & 15;

    f32x4 acc[NT];
    #pragma unroll
    for (int nt = 0; nt < NT; ++nt)
        #pragma unroll
        for (int i = 0; i < 4; ++i) acc[nt][i] = 0.f;

    const int ar = tid >> 2, aseg = tid & 3;

    for (int k0 = 0; k0 < K; k0 += 32) {
        __syncthreads();
        uint4 va = *(const uint4*)(Ab + (size_t)(rowBase + ar) * K + k0 + aseg * 8);
        *(uint4*)(As + ar * LDA + aseg * 8) = va;
        if (tid < NTILE * 4) {
            int r = tid >> 2, seg = tid & 3;
            uint4 vb = *(const uint4*)(Bb + (size_t)(colBase + r) * K + k0 + seg * 8);
            *(uint4*)(Bs + r * LDA + seg * 8) = vb;
        }
        __syncthreads();
        short8 a = *(const short8*)(As + (wave * 16 + l16) * LDA + quad * 8);
        #pragma unroll
        for (int nt = 0; nt < NT; ++nt) {
            short8 bf = *(const short8*)(Bs + (nt * 16 + l16) * LDA + quad * 8);
            acc[nt] = __builtin_amdgcn_mfma_f32_16x16x32_bf16(a, bf, acc[nt], 0, 0, 0);
        }
    }

    const int px0 = rowBase + wave * 16 + quad * 4;
    #pragma unroll
    for (int nt = 0; nt < NT; ++nt) {
        const int co = colBase + nt * 16 + l16;
        float sc = 0.f, bb = 0.f;
        if (EPI == 1) {
            sc = p0[co] * rsqrtf(p3[co] + 1e-5f);
            bb = p1[co] - p2[co] * sc;
        } else if (EPI == 2) {
            bb = p0[co];
        }
        float o[4];
        #pragma unroll
        for (int r = 0; r < 4; ++r) {
            float xv = acc[nt][r];
            if (EPI == 1) {
                xv = xv * sc + bb;
                xv = xv / (1.f + __expf(-xv));
            } else if (EPI == 2) {
                xv += bb;
                xv = (xv > 20.f) ? xv : log1pf(__expf(xv));
            } else if (EPI == 3) {
                xv = xv / (1.f + __expf(-xv));
            }
            o[r] = xv;
        }
        if (OUTM == 3) {
            *(float4*)((float*)C + (size_t)co * M + px0) =
                make_float4(o[0], o[1], o[2], o[3]);
        } else if (OUTM == 4) {
            uint2 pk;
            pk.x = (unsigned)f2b(o[0]) | ((unsigned)f2b(o[1]) << 16);
            pk.y = (unsigned)f2b(o[2]) | ((unsigned)f2b(o[3]) << 16);
            *(uint2*)((u16*)C + (size_t)co * M + px0) = pk;
        } else if (OUTM == 2) {
            #pragma unroll
            for (int r = 0; r < 4; ++r)
                ((u16*)C)[(size_t)(px0 + r) * N + co] = f2b(o[r]);
        } else {
            #pragma unroll
            for (int r = 0; r < 4; ++r)
                ((float*)C)[(size_t)(px0 + r) * N + co] = o[r];
        }
    }
}

template<int NTILE, int EPI, int OUTM>
__global__ __launch_bounds__(256) void gemm_mfma_k(
    int M, int N, int K,
    const u16* __restrict__ Ab, const u16* __restrict__ Bb, void* __restrict__ C,
    const float* __restrict__ p0, const float* __restrict__ p1,
    const float* __restrict__ p2, const float* __restrict__ p3)
{
    __shared__ u16 As[64 * 40];
    __shared__ u16 Bs[NTILE * 40];
    gemm_body<NTILE, EPI, OUTM>(M, N, K, Ab, Bb, C, p0, p1, p2, p3,
                                blockIdx.x * 64, blockIdx.y * NTILE, As, Bs);
}

// ---------------- combined in-proj: x-half -> bf16 rowmajor; z-half -> bf16 transposed+SiLU ----------------
__global__ __launch_bounds__(256) void ip_k(
    const u16* __restrict__ t2b, const u16* __restrict__ inwb,
    u16* __restrict__ xzb16, u16* __restrict__ zst16)
{
    __shared__ u16 As[64 * 40];
    __shared__ u16 Bs[64 * 40];
    if (blockIdx.y < 6) {
        gemm_body<64, 0, 2>(8192, 384, 192, t2b, inwb, xzb16,
                            nullptr, nullptr, nullptr, nullptr,
                            blockIdx.x * 64, blockIdx.y * 64, As, Bs);
    } else {
        gemm_body<64, 3, 4>(8192, 384, 192, t2b, inwb + (size_t)384*192, zst16,
                            nullptr, nullptr, nullptr, nullptr,
                            blockIdx.x * 64, (blockIdx.y - 6) * 64, As, Bs);
    }
}

// ---------------- combined x-proj + dt dispatch ----------------
__global__ __launch_bounds__(256) void pd_k(
    const u16* __restrict__ xcb, const u16* __restrict__ Wdt,
    const u16* __restrict__ xpb, const float* __restrict__ dt_b,
    float* __restrict__ dtt, float* __restrict__ dblt)
{
    __shared__ u16 As[64 * 40];
    __shared__ u16 Bs[64 * 40];
    if (blockIdx.y < 6) {
        gemm_body<64, 2, 3>(8192, 384, 384, xcb, Wdt, dtt, dt_b, nullptr, nullptr, nullptr,
                            blockIdx.x * 64, blockIdx.y * 64, As, Bs);
    } else {
        gemm_body<32, 0, 3>(8192, 32, 384, xcb, xpb, dblt, nullptr, nullptr, nullptr, nullptr,
                            blockIdx.x * 64, 0, As, Bs);
    }
}

// ---------------- out-proj GEMM with transposed-f32 A staging ----------------
__global__ __launch_bounds__(256) void gemm_at_k(
    int M, int N, int K,
    const float* __restrict__ At, const u16* __restrict__ Bb, u16* __restrict__ C,
    const float* __restrict__ p0, const float* __restrict__ p1,
    const float* __restrict__ p2, const float* __restrict__ p3)
{
    constexpr int LDA = 40;
    constexpr int NTILE = 64, NT = 4;
    __shared__ u16 As[64 * LDA];
    __shared__ u16 Bs[NTILE * LDA];
    const int tid = threadIdx.x;
    const int wave = tid >> 6, lane = tid & 63;
    const int quad = lane >> 4, l16 = lane & 15;
    const int rowBase = blockIdx.x * 64;
    const int colBase = blockIdx.y * NTILE;

    f32x4 acc[NT];
    #pragma unroll
    for (int nt = 0; nt < NT; ++nt)
        #pragma unroll
        for (int i = 0; i < 4; ++i) acc[nt][i] = 0.f;

    const int krow = tid >> 3, mseg = tid & 7;

    for (int k0 = 0; k0 < K; k0 += 32) {
        __syncthreads();
        const float* src = At + (size_t)(k0 + krow) * M + rowBase + mseg * 4;
        float4 f0 = *(const float4*)(src);
        float4 f1 = *(const float4*)(src + 32);
        As[(mseg*4 + 0) * LDA + krow] = f2b(f0.x);
        As[(mseg*4 + 1) * LDA + krow] = f2b(f0.y);
        As[(mseg*4 + 2) * LDA + krow] = f2b(f0.z);
        As[(mseg*4 + 3) * LDA + krow] = f2b(f0.w);
        As[(mseg*4 + 32) * LDA + krow] = f2b(f1.x);
        As[(mseg*4 + 33) * LDA + krow] = f2b(f1.y);
        As[(mseg*4 + 34) * LDA + krow] = f2b(f1.z);
        As[(mseg*4 + 35) * LDA + krow] = f2b(f1.w);
        if (tid < NTILE * 4) {
            int r = tid >> 2, seg = tid & 3;
            uint4 vb = *(const uint4*)(Bb + (size_t)(colBase + r) * K + k0 + seg * 8);
            *(uint4*)(Bs + r * LDA + seg * 8) = vb;
        }
        __syncthreads();
        short8 a = *(const short8*)(As + (wave * 16 + l16) * LDA + quad * 8);
        #pragma unroll
        for (int nt = 0; nt < NT; ++nt) {
            short8 bf = *(const short8*)(Bs + (nt * 16 + l16) * LDA + quad * 8);
            acc[nt] = __builtin_amdgcn_mfma_f32_16x16x32_bf16(a, bf, acc[nt], 0, 0, 0);
        }
    }

    const int px0 = rowBase + wave * 16 + quad * 4;
    #pragma unroll
    for (int nt = 0; nt < NT; ++nt) {
        const int co = colBase + nt * 16 + l16;
        const float sc = p0[co] * rsqrtf(p3[co] + 1e-5f);
        const float bb = p1[co] - p2[co] * sc;
        #pragma unroll
        for (int r = 0; r < 4; ++r) {
            float xv = acc[nt][r] * sc + bb;
            xv = xv / (1.f + __expf(-xv));
            C[(size_t)(px0 + r) * N + co] = f2b(xv);
        }
    }
}

// ---------------- depthwise causal conv (K=4) + SiLU, bf16 in/out ----------------
__global__ __launch_bounds__(256) void dwconv_k(
    const u16* __restrict__ xz16, const float* __restrict__ cw, const float* __restrict__ cb,
    u16* __restrict__ xcb, u16* __restrict__ xct16)
{
    __shared__ float T[64][65];
    const int tid = threadIdx.x;
    const int cl = tid & 63, rq = tid >> 6;
    const int mBase = blockIdx.x * 64, cBase = blockIdx.y * 64;
    const int c = cBase + cl;
    const float w0 = cw[c*4+0], w1 = cw[c*4+1], w2 = cw[c*4+2], w3 = cw[c*4+3];
    const float bias = cb[c];
    #pragma unroll
    for (int rr = 0; rr < 16; ++rr) {
        int ml = rr * 4 + rq;
        int bl = mBase + ml;
        int l = bl & 1023;
        float acc = bias + b2f(xz16[(size_t)bl * 384 + c]) * w3;
        if (l >= 1) acc += b2f(xz16[(size_t)(bl-1) * 384 + c]) * w2;
        if (l >= 2) acc += b2f(xz16[(size_t)(bl-2) * 384 + c]) * w1;
        if (l >= 3) acc += b2f(xz16[(size_t)(bl-3) * 384 + c]) * w0;
        float s = acc / (1.f + __expf(-acc));
        xcb[(size_t)bl * DI_ + c] = f2b(s);
        T[ml][cl] = s;
    }
    __syncthreads();
    #pragma unroll
    for (int rr = 0; rr < 16; ++rr) {
        int dl = rr * 4 + rq;
        xct16[(size_t)(cBase + dl) * 8192 + mBase + cl] = f2b(T[cl][dl]);
    }
}

// ---------------- selective scan: LDS-combine, exp-of-sum trick; bf16 xc/z ----------------
__global__ __launch_bounds__(256) void scan_k(
    const float* __restrict__ dtt, const float* __restrict__ dblt,
    const u16* __restrict__ xct16, const u16* __restrict__ zst16,
    const float* __restrict__ A_log, const float* __restrict__ Dp,
    float* __restrict__ yft)
{
    const int bd = blockIdx.x;
    const int b = bd / DI_, d = bd % DI_;
    const int tid = threadIdx.x;
    const size_t tb = (size_t)d * 8192 + (size_t)b * 1024;
    const size_t nb = (size_t)b * 1024;
    const int t4 = tid * 4;

    __shared__ float LH[16][257];
    __shared__ float SD[257];
    __shared__ float SH[16][17];
    __shared__ float SP[16][17];
    __shared__ float SSD[17];
    __shared__ float AndS[16];

    const float4 dt4 = *(const float4*)(dtt + tb + t4);
    const uint2 xcu = *(const uint2*)(xct16 + tb + t4);
    const float xc0 = b2f_lo(xcu.x), xc1 = b2f_hi(xcu.x);
    const float xc2 = b2f_lo(xcu.y), xc3 = b2f_hi(xcu.y);
    const float dtxc[4] = {dt4.x*xc0, dt4.y*xc1, dt4.z*xc2, dt4.w*xc3};

    float And[16];
    #pragma unroll
    for (int n = 0; n < 16; ++n) And[n] = -__expf(A_log[d*16 + n]);
    if (tid < 16) AndS[tid] = -__expf(A_log[d*16 + tid]);
    SD[tid] = dt4.x + dt4.y + dt4.z + dt4.w;

    #pragma unroll
    for (int n = 0; n < 16; ++n) {
        const float4 bs4 = *(const float4*)(dblt + (size_t)n * 8192 + nb + t4);
        float h = dtxc[0] * bs4.x;
        h = __expf(dt4.y * And[n]) * h + dtxc[1] * bs4.y;
        h = __expf(dt4.z * And[n]) * h + dtxc[2] * bs4.z;
        h = __expf(dt4.w * And[n]) * h + dtxc[3] * bs4.w;
        LH[n][tid] = h;
    }
    __syncthreads();

    {
        const int n = tid & 15, s = tid >> 4;
        const float An = AndS[n];
        float H = 0.f, ssd = 0.f;
        #pragma unroll
        for (int k = 0; k < 16; ++k) {
            const int c = s * 16 + k;
            float sd = SD[c];
            H = __expf(An * sd) * H + LH[n][c];
            ssd += sd;
        }
        SH[n][s] = H;
        if (n == 0) SSD[s] = ssd;
    }
    __syncthreads();

    if (tid < 16) {
        const float An = AndS[tid];
        float Hp = 0.f;
        #pragma unroll
        for (int s = 0; s < 16; ++s) {
            SP[tid][s] = Hp;
            Hp = __expf(An * SSD[s]) * Hp + SH[tid][s];
        }
    }
    __syncthreads();

    {
        const int n = tid & 15, s = tid >> 4;
        const float An = AndS[n];
        float st = SP[n][s];
        #pragma unroll
        for (int k = 0; k < 16; ++k) {
            const int c = s * 16 + k;
            float a = __expf(An * SD[c]);
            float h = LH[n][c];
            LH[n][c] = st;
            st = a * st + h;
        }
    }
    __syncthreads();

    float y0 = 0.f, y1 = 0.f, y2 = 0.f, y3 = 0.f;
    #pragma unroll
    for (int n = 0; n < 16; ++n) {
        float h = LH[n][tid];
        const float4 bs4 = *(const float4*)(dblt + (size_t)n * 8192 + nb + t4);
        const float4 cs4 = *(const float4*)(dblt + (size_t)(16 + n) * 8192 + nb + t4);
        h = __expf(dt4.x * And[n]) * h + dtxc[0]*bs4.x; y0 += h * cs4.x;
        h = __expf(dt4.y * And[n]) * h + dtxc[1]*bs4.y; y1 += h * cs4.y;
        h = __expf(dt4.z * And[n]) * h + dtxc[2]*bs4.z; y2 += h * cs4.z;
        h = __expf(dt4.w * And[n]) * h + dtxc[3]*bs4.w; y3 += h * cs4.w;
    }
    const float dp = Dp[d];
    const uint2 zsu = *(const uint2*)(zst16 + tb + t4);
    float4 o;
    o.x = (y0 + xc0 * dp) * b2f_lo(zsu.x);
    o.y = (y1 + xc1 * dp) * b2f_hi(zsu.x);
    o.z = (y2 + xc2 * dp) * b2f_lo(zsu.y);
    o.w = (y3 + xc3 * dp) * b2f_hi(zsu.y);
    *(float4*)(yft + tb + t4) = o;
}

extern "C" void kernel_launch(void* const* d_in, const int* in_sizes, int n_in,
                              void* d_out, int out_size, void* d_ws, size_t ws_size,
                              hipStream_t stream) {
    const float* x     = (const float*)d_in[0];
    const float* w1    = (const float*)d_in[1];
    const float* g1    = (const float*)d_in[2];
    const float* b1    = (const float*)d_in[3];
    const float* m1    = (const float*)d_in[4];
    const float* v1    = (const float*)d_in[5];
    const float* w2    = (const float*)d_in[6];
    const float* g2    = (const float*)d_in[7];
    const float* b2    = (const float*)d_in[8];
    const float* m2    = (const float*)d_in[9];
    const float* v2    = (const float*)d_in[10];
    const float* in_w  = (const float*)d_in[11];
    const float* cw    = (const float*)d_in[12];
    const float* cb    = (const float*)d_in[13];
    const float* xp_w  = (const float*)d_in[14];
    const float* dt_w  = (const float*)d_in[15];
    const float* dt_b  = (const float*)d_in[16];
    const float* A_log = (const float*)d_in[17];
    const float* Dp    = (const float*)d_in[18];
    const float* out_w = (const float*)d_in[19];
    const float* w3    = (const float*)d_in[20];
    const float* g3    = (const float*)d_in[21];
    const float* b3    = (const float*)d_in[22];
    const float* m3    = (const float*)d_in[23];
    const float* v3    = (const float*)d_in[24];
    const float* w4    = (const float*)d_in[25];
    const float* g4    = (const float*)d_in[26];
    const float* b4    = (const float*)d_in[27];
    const float* m4    = (const float*)d_in[28];
    const float* v4    = (const float*)d_in[29];

    float* ws   = (float*)d_ws;
    u16*   xzb16 = (u16*)(ws + O_XZ);
    u16*   xct16 = (u16*)(ws + O_XCT);
    u16*   zst16 = (u16*)(ws + O_ZST);
    float* dblt = ws + O_DBLT;
    float* yft  = ws + O_YFT;
    float* dtt  = ws + O_DTT;
    u16* b16  = (u16*)(ws + O_B16);
    u16* t1b  = b16 + B_T1;
    u16* t2b  = b16 + B_T2;
    u16* xcb  = b16 + B_XC;
    u16* Xb1  = b16 + B_XB1;
    u16* Xb4  = b16 + B_XB4;
    u16* wt1  = b16 + B_WT1;
    u16* wt4  = b16 + B_WT4;
    u16* inwb = b16 + B_INW;
    u16* w2b  = b16 + B_W2;
    u16* xpb  = b16 + B_XP;
    u16* Wdt  = b16 + B_WDT;
    u16* Wow  = b16 + B_WOW;

    // 0) weight prep + input convert (8 jobs)
    PrepArgs pa;
    pa.w1 = w1; pa.w4 = w4; pa.in_w = in_w; pa.w2 = w2; pa.xp_w = xp_w;
    pa.dt_w = dt_w; pa.w3 = w3; pa.out_w = out_w; pa.x = x;
    pa.wt1 = wt1; pa.wt4 = wt4; pa.inwb = inwb; pa.w2b = w2b; pa.xpb = xpb;
    pa.Wdt = Wdt; pa.Wow = Wow; pa.Xb1 = Xb1;
    prep_k<<<dim3(256, 8), 256, 0, stream>>>(pa);

    // 1) conv3x3 96->96 + BN + GELU (halo MFMA) -> t1 bf16 NHWC
    conv3x3_mfma_k<96, 96, 32, 2><<<dim3(128, 3), 256, 0, stream>>>(
        Xb1, wt1, g1, b1, m1, v1, t1b);

    // 2) 1x1 conv 96->192 + BN + SiLU -> t2 bf16
    gemm_mfma_k<64, 1, 2><<<dim3(128, 3), 256, 0, stream>>>(
        8192, 192, 96, t1b, w2b, t2b, g2, b2, m2, v2);

    // 3) in-proj: x-half -> xzb16 bf16 row-major; z-half + SiLU -> zst16 bf16 transposed
    ip_k<<<dim3(128, 12), 256, 0, stream>>>(t2b, inwb, xzb16, zst16);

    // 4) depthwise causal conv + SiLU -> xcb bf16 + xct16 bf16 transposed
    dwconv_k<<<dim3(128, 6), 256, 0, stream>>>(xzb16, cw, cb, xcb, xct16);

    // 5) combined: dt (y<6) + x-proj Bs/Cs (y==6) -> dtt f32, dblt f32 (transposed)
    pd_k<<<dim3(128, 7), 256, 0, stream>>>(xcb, Wdt, xpb, dt_b, dtt, dblt);

    // 6) selective scan + gate -> yft [384][8192] f32
    scan_k<<<8 * DI_, 256, 0, stream>>>(dtt, dblt, xct16, zst16, A_log, Dp, yft);

    // 7) fused out-proj + 1x1 conv3 + BN + SiLU (transposed-A MFMA) -> Xb4 bf16
    gemm_at_k<<<dim3(128, 3), 256, 0, stream>>>(
        8192, 192, 384, yft, Wow, Xb4, g3, b3, m3, v3);

    // 8) conv3x3 192->192 + BN + GELU (halo MFMA) -> out f32 NCHW (coalesced)
    conv3x3_mfma_k<192, 192, 32, 1><<<dim3(128, 6), 256, 0, stream>>>(
        Xb4, wt4, g4, b4, m4, v4, (float*)d_out);
}